// Round 1
// baseline (354.773 us; speedup 1.0000x reference)
//
#include <hip/hip_runtime.h>
#include <hip/hip_bf16.h>

typedef __bf16 bf16_t;
typedef __bf16 bf16x8 __attribute__((ext_vector_type(8)));
typedef float f32x4 __attribute__((ext_vector_type(4)));

#define D_MODEL 1024
#define HEADS 16
#define D_K 64
#define SEQ 2048
#define BATCH 2
#define MTOT (SEQ * BATCH) /* 4096 */
#define QSCALE 0.125f

// ------------------------------------------------------------------
// fp32 -> bf16 convert (vectorized, 8 elems/thread)
// ------------------------------------------------------------------
__global__ __launch_bounds__(256) void cvt_kernel(const float* __restrict__ src,
                                                  bf16_t* __restrict__ dst, int n) {
  int i = (blockIdx.x * 256 + threadIdx.x) * 8;
  if (i >= n) return;
  float4 a = *(const float4*)(src + i);
  float4 b = *(const float4*)(src + i + 4);
  bf16x8 v;
  v[0] = (bf16_t)a.x; v[1] = (bf16_t)a.y; v[2] = (bf16_t)a.z; v[3] = (bf16_t)a.w;
  v[4] = (bf16_t)b.x; v[5] = (bf16_t)b.y; v[6] = (bf16_t)b.z; v[7] = (bf16_t)b.w;
  *(bf16x8*)(dst + i) = v;
}

// ------------------------------------------------------------------
// GEMM: C[m][n] = X[m,:] . W[n,:] + bias[n]   (x @ W^T + b)
// M=4096, N=1024, K=1024. 128x128 tile, 4 waves each 64x64, BK=64.
// MODE 0: bf16 out to [B,H,S,64]   (Q/K attention layout, * scale)
// MODE 1: bf16 out to [B,H,64,S]   (V transposed layout, * scale)
// MODE 2: fp32 out row-major [M,N] (final output)
// ------------------------------------------------------------------
#define GBK 64
#define LDK 72  // padded LDS stride (bf16 elems): bank-uniform b128 reads

template <int MODE>
__global__ __launch_bounds__(256) void gemm_bt(const bf16_t* __restrict__ X,
                                               const bf16_t* __restrict__ W,
                                               const float* __restrict__ bias,
                                               void* __restrict__ outp, float scale) {
  __shared__ __align__(16) bf16_t As[128 * LDK];
  __shared__ __align__(16) bf16_t Bs[128 * LDK];
  const int t = threadIdx.x;
  const int m0 = blockIdx.y * 128, n0 = blockIdx.x * 128;
  const int w = t >> 6, l = t & 63, lr = l & 15, lg = l >> 4;
  const int wm = (w >> 1) * 64, wn = (w & 1) * 64;

  f32x4 acc[4][4] = {};

  for (int kt = 0; kt < D_MODEL; kt += GBK) {
#pragma unroll
    for (int p = 0; p < 4; ++p) {
      int id = p * 256 + t;
      int row = id >> 3, ck = (id & 7) * 8;
      *(int4*)(&As[row * LDK + ck]) = *(const int4*)(&X[(size_t)(m0 + row) * D_MODEL + kt + ck]);
      *(int4*)(&Bs[row * LDK + ck]) = *(const int4*)(&W[(size_t)(n0 + row) * D_MODEL + kt + ck]);
    }
    __syncthreads();
#pragma unroll
    for (int kk = 0; kk < 2; ++kk) {
      bf16x8 a[4], b[4];
#pragma unroll
      for (int i = 0; i < 4; ++i)
        a[i] = *(const bf16x8*)(&As[(wm + i * 16 + lr) * LDK + kk * 32 + lg * 8]);
#pragma unroll
      for (int j = 0; j < 4; ++j)
        b[j] = *(const bf16x8*)(&Bs[(wn + j * 16 + lr) * LDK + kk * 32 + lg * 8]);
#pragma unroll
      for (int i = 0; i < 4; ++i)
#pragma unroll
        for (int j = 0; j < 4; ++j)
          acc[i][j] = __builtin_amdgcn_mfma_f32_16x16x32_bf16(a[i], b[j], acc[i][j], 0, 0, 0);
    }
    __syncthreads();
  }

  // epilogue: D layout col = lane&15, row = (lane>>4)*4 + reg  [m89-verified]
#pragma unroll
  for (int i = 0; i < 4; ++i) {
#pragma unroll
    for (int j = 0; j < 4; ++j) {
      int col = n0 + wn + j * 16 + lr;
      float bb = bias[col];
#pragma unroll
      for (int ii = 0; ii < 4; ++ii) {
        int row = m0 + wm + i * 16 + lg * 4 + ii;
        float v = acc[i][j][ii];
        if (MODE == 2) {
          ((float*)outp)[(size_t)row * D_MODEL + col] = v + bb;
        } else {
          v = (v + bb) * scale;
          int s = row >> 1, b2 = row & 1, h = col >> 6, d = col & 63;
          if (MODE == 0)
            ((bf16_t*)outp)[(((size_t)(b2 * HEADS + h) * SEQ) + s) * D_K + d] = (bf16_t)v;
          else
            ((bf16_t*)outp)[(((size_t)(b2 * HEADS + h) * D_K) + d) * SEQ + s] = (bf16_t)v;
        }
      }
    }
  }
}

// ------------------------------------------------------------------
// Flash attention with relative-position bias.
// grid = (SEQ/64, B*H). 4 waves, each owns 16 q-rows. K-tiles of 64.
// Q pre-scaled by 1/8 in projection. bias[q,k] = tbl[q - k + 2047] per head.
// ------------------------------------------------------------------
#define TBL_N 2111

__global__ __launch_bounds__(256) void attn_kernel(const bf16_t* __restrict__ Qa,
                                                   const bf16_t* __restrict__ Ka,
                                                   const bf16_t* __restrict__ Vt,
                                                   const float* __restrict__ rel,
                                                   bf16_t* __restrict__ ctx) {
  __shared__ float tbl[TBL_N + 1];
  __shared__ __align__(16) bf16_t p_lds[4][16 * 72];  // per-wave P tile, padded

  const int qb = blockIdx.x, bh = blockIdx.y;
  const int h = bh & (HEADS - 1);
  const int b2 = bh >> 4;
  const int qbase = qb * 64;
  const int t = threadIdx.x, w = t >> 6, l = t & 63, lr = l & 15, lg = l >> 4;

  for (int j = t; j < TBL_N; j += 256) tbl[j] = rel[(qbase + j) * HEADS + h];
  __syncthreads();

  const bf16_t* Qbh = Qa + (size_t)bh * SEQ * D_K;
  const bf16_t* Kbh = Ka + (size_t)bh * SEQ * D_K;
  const bf16_t* Vbh = Vt + (size_t)bh * D_K * SEQ;

  bf16x8 qf[2];
#pragma unroll
  for (int kk = 0; kk < 2; ++kk)
    qf[kk] = *(const bf16x8*)(&Qbh[(size_t)(qbase + w * 16 + lr) * D_K + kk * 32 + lg * 8]);

  float m_run[4], l_run[4];
  f32x4 acc_o[4] = {};
#pragma unroll
  for (int i = 0; i < 4; ++i) { m_run[i] = -3.0e38f; l_run[i] = 0.f; }

  bf16_t* pw = p_lds[w];

  for (int kt = 0; kt < SEQ; kt += 64) {
    // ---- QK^T for 16 q-rows x 64 k-cols ----
    f32x4 sc[4];
#pragma unroll
    for (int c = 0; c < 4; ++c) {
      f32x4 z = {};
#pragma unroll
      for (int kk = 0; kk < 2; ++kk) {
        bf16x8 kf = *(const bf16x8*)(&Kbh[(size_t)(kt + c * 16 + lr) * D_K + kk * 32 + lg * 8]);
        z = __builtin_amdgcn_mfma_f32_16x16x32_bf16(qf[kk], kf, z, 0, 0, 0);
      }
      sc[c] = z;
    }
    // ---- + bias, row max ----
    float s_val[4][4];
    float vmax[4];
#pragma unroll
    for (int i = 0; i < 4; ++i) vmax[i] = -3.0e38f;
#pragma unroll
    for (int c = 0; c < 4; ++c) {
      int kg = kt + c * 16 + lr;
#pragma unroll
      for (int i = 0; i < 4; ++i) {
        int qloc = w * 16 + lg * 4 + i;
        float s = sc[c][i] + tbl[qloc - kg + 2047];
        s_val[c][i] = s;
        vmax[i] = fmaxf(vmax[i], s);
      }
    }
#pragma unroll
    for (int i = 0; i < 4; ++i)
#pragma unroll
      for (int off = 1; off < 16; off <<= 1)
        vmax[i] = fmaxf(vmax[i], __shfl_xor(vmax[i], off));

    float m_new[4], alpha[4], vsum[4];
#pragma unroll
    for (int i = 0; i < 4; ++i) {
      m_new[i] = fmaxf(m_run[i], vmax[i]);
      alpha[i] = __expf(m_run[i] - m_new[i]);
      vsum[i] = 0.f;
    }
    // ---- P = exp(s - m), store bf16 to LDS (A-operand bounce) ----
#pragma unroll
    for (int c = 0; c < 4; ++c) {
#pragma unroll
      for (int i = 0; i < 4; ++i) {
        float p = __expf(s_val[c][i] - m_new[i]);
        bf16_t pb = (bf16_t)p;
        vsum[i] += (float)pb;  // denominator consistent with bf16 numerator
        pw[(lg * 4 + i) * 72 + c * 16 + lr] = pb;
      }
    }
#pragma unroll
    for (int i = 0; i < 4; ++i) {
#pragma unroll
      for (int off = 1; off < 16; off <<= 1) vsum[i] += __shfl_xor(vsum[i], off);
      l_run[i] = l_run[i] * alpha[i] + vsum[i];
      m_run[i] = m_new[i];
    }
    // ---- rescale O ----
#pragma unroll
    for (int c = 0; c < 4; ++c)
#pragma unroll
      for (int i = 0; i < 4; ++i) acc_o[c][i] *= alpha[i];

    asm volatile("s_waitcnt lgkmcnt(0)" ::: "memory");

    // ---- PV: O += P @ V ----
#pragma unroll
    for (int kk = 0; kk < 2; ++kk) {
      bf16x8 pa = *(const bf16x8*)(&pw[lr * 72 + kk * 32 + lg * 8]);
#pragma unroll
      for (int c = 0; c < 4; ++c) {
        bf16x8 vf = *(const bf16x8*)(&Vbh[(size_t)(c * 16 + lr) * SEQ + kt + kk * 32 + lg * 8]);
        acc_o[c] = __builtin_amdgcn_mfma_f32_16x16x32_bf16(pa, vf, acc_o[c], 0, 0, 0);
      }
    }
  }

  // ---- normalize, write ctx[m=(s,b)][h*64+d] bf16 ----
#pragma unroll
  for (int i = 0; i < 4; ++i) {
    float inv = 1.0f / l_run[i];
    int qg = qbase + w * 16 + lg * 4 + i;
    size_t base = ((size_t)qg * BATCH + b2) * D_MODEL + h * D_K;
#pragma unroll
    for (int c = 0; c < 4; ++c)
      ctx[base + c * 16 + lr] = (bf16_t)(acc_o[c][i] * inv);
  }
}

// ------------------------------------------------------------------
extern "C" void kernel_launch(void* const* d_in, const int* in_sizes, int n_in,
                              void* d_out, int out_size, void* d_ws, size_t ws_size,
                              hipStream_t stream) {
  const float* query = (const float*)d_in[0];
  const float* key_i = (const float*)d_in[1];
  const float* value = (const float*)d_in[2];
  const float* Wq = (const float*)d_in[3];
  const float* bq = (const float*)d_in[4];
  const float* Wk = (const float*)d_in[5];
  const float* bk = (const float*)d_in[6];
  const float* Wv = (const float*)d_in[7];
  const float* bv = (const float*)d_in[8];
  const float* Wo = (const float*)d_in[9];
  const float* bo = (const float*)d_in[10];
  const float* rel = (const float*)d_in[11];
  float* out = (float*)d_out;

  char* ws = (char*)d_ws;
  size_t off = 0;
  auto alloc = [&](size_t bytes) {
    char* p = ws + off;
    off = (off + bytes + 255) & ~(size_t)255;
    return p;
  };
  const size_t nIn = (size_t)MTOT * D_MODEL;   // 4,194,304
  const size_t nW = (size_t)D_MODEL * D_MODEL; // 1,048,576

  bf16_t* Xq = (bf16_t*)alloc(nIn * 2);
  bf16_t* Xk = (bf16_t*)alloc(nIn * 2);
  bf16_t* Xv = (bf16_t*)alloc(nIn * 2);
  bf16_t* Wqb = (bf16_t*)alloc(nW * 2);
  bf16_t* Wkb = (bf16_t*)alloc(nW * 2);
  bf16_t* Wvb = (bf16_t*)alloc(nW * 2);
  bf16_t* Wob = (bf16_t*)alloc(nW * 2);
  bf16_t* qa = (bf16_t*)alloc(nIn * 2);   // [B,H,S,64]
  bf16_t* ka = (bf16_t*)alloc(nIn * 2);   // [B,H,S,64]
  bf16_t* vt = (bf16_t*)alloc(nIn * 2);   // [B,H,64,S]
  bf16_t* ctx = (bf16_t*)alloc(nIn * 2);  // [M,1024]

  cvt_kernel<<<nIn / 2048, 256, 0, stream>>>(query, Xq, (int)nIn);
  cvt_kernel<<<nIn / 2048, 256, 0, stream>>>(key_i, Xk, (int)nIn);
  cvt_kernel<<<nIn / 2048, 256, 0, stream>>>(value, Xv, (int)nIn);
  cvt_kernel<<<nW / 2048, 256, 0, stream>>>(Wq, Wqb, (int)nW);
  cvt_kernel<<<nW / 2048, 256, 0, stream>>>(Wk, Wkb, (int)nW);
  cvt_kernel<<<nW / 2048, 256, 0, stream>>>(Wv, Wvb, (int)nW);
  cvt_kernel<<<nW / 2048, 256, 0, stream>>>(Wo, Wob, (int)nW);

  dim3 gg(D_MODEL / 128, MTOT / 128);
  gemm_bt<0><<<gg, 256, 0, stream>>>(Xq, Wqb, bq, qa, QSCALE);
  gemm_bt<0><<<gg, 256, 0, stream>>>(Xk, Wkb, bk, ka, 1.0f);
  gemm_bt<1><<<gg, 256, 0, stream>>>(Xv, Wvb, bv, vt, 1.0f);

  dim3 ga(SEQ / 64, BATCH * HEADS);
  attn_kernel<<<ga, 256, 0, stream>>>(qa, ka, vt, rel, ctx);

  gemm_bt<2><<<gg, 256, 0, stream>>>(ctx, Wob, bo, out, 1.0f);
}

// Round 2
// 349.611 us; speedup vs baseline: 1.0148x; 1.0148x over previous
//
#include <hip/hip_runtime.h>
#include <hip/hip_bf16.h>

typedef __bf16 bf16_t;
typedef __bf16 bf16x8 __attribute__((ext_vector_type(8)));
typedef __bf16 bf16x4 __attribute__((ext_vector_type(4)));
typedef float f32x4 __attribute__((ext_vector_type(4)));

#define D_MODEL 1024
#define HEADS 16
#define D_K 64
#define SEQ 2048
#define BATCH 2
#define MTOT (SEQ * BATCH) /* 4096 */
#define QSCALE 0.125f

// ------------------------------------------------------------------
// fp32 -> bf16 convert (vectorized, 8 elems/thread)
// ------------------------------------------------------------------
__global__ __launch_bounds__(256) void cvt_kernel(const float* __restrict__ src,
                                                  bf16_t* __restrict__ dst, int n) {
  int i = (blockIdx.x * 256 + threadIdx.x) * 8;
  if (i >= n) return;
  float4 a = *(const float4*)(src + i);
  float4 b = *(const float4*)(src + i + 4);
  bf16x8 v;
  v[0] = (bf16_t)a.x; v[1] = (bf16_t)a.y; v[2] = (bf16_t)a.z; v[3] = (bf16_t)a.w;
  v[4] = (bf16_t)b.x; v[5] = (bf16_t)b.y; v[6] = (bf16_t)b.z; v[7] = (bf16_t)b.w;
  *(bf16x8*)(dst + i) = v;
}

// ------------------------------------------------------------------
// GEMM: C[m][n] = X[m,:] . W[n,:] + bias[n]   (x @ W^T + b)
// M=4096, N=1024, K=1024. 128x128 tile, 4 waves each 64x64, BK=64.
// MODE 0: bf16 out to [B,H,S,64]   (Q/K attention layout, * scale)
// MODE 1: bf16 out to [B,H,64,S]   (V transposed layout, * scale)
// MODE 2: fp32 out row-major [M,N] (final output)
// ------------------------------------------------------------------
#define GBK 64
#define LDK 72  // padded LDS stride (bf16 elems): bank-uniform b128 reads

template <int MODE>
__global__ __launch_bounds__(256) void gemm_bt(const bf16_t* __restrict__ X,
                                               const bf16_t* __restrict__ W,
                                               const float* __restrict__ bias,
                                               void* __restrict__ outp, float scale) {
  __shared__ __align__(16) bf16_t As[128 * LDK];
  __shared__ __align__(16) bf16_t Bs[128 * LDK];
  const int t = threadIdx.x;
  const int m0 = blockIdx.y * 128, n0 = blockIdx.x * 128;
  const int w = t >> 6, l = t & 63, lr = l & 15, lg = l >> 4;
  const int wm = (w >> 1) * 64, wn = (w & 1) * 64;

  f32x4 acc[4][4] = {};

  for (int kt = 0; kt < D_MODEL; kt += GBK) {
#pragma unroll
    for (int p = 0; p < 4; ++p) {
      int id = p * 256 + t;
      int row = id >> 3, ck = (id & 7) * 8;
      *(int4*)(&As[row * LDK + ck]) = *(const int4*)(&X[(size_t)(m0 + row) * D_MODEL + kt + ck]);
      *(int4*)(&Bs[row * LDK + ck]) = *(const int4*)(&W[(size_t)(n0 + row) * D_MODEL + kt + ck]);
    }
    __syncthreads();
#pragma unroll
    for (int kk = 0; kk < 2; ++kk) {
      bf16x8 a[4], b[4];
#pragma unroll
      for (int i = 0; i < 4; ++i)
        a[i] = *(const bf16x8*)(&As[(wm + i * 16 + lr) * LDK + kk * 32 + lg * 8]);
#pragma unroll
      for (int j = 0; j < 4; ++j)
        b[j] = *(const bf16x8*)(&Bs[(wn + j * 16 + lr) * LDK + kk * 32 + lg * 8]);
#pragma unroll
      for (int i = 0; i < 4; ++i)
#pragma unroll
        for (int j = 0; j < 4; ++j)
          acc[i][j] = __builtin_amdgcn_mfma_f32_16x16x32_bf16(a[i], b[j], acc[i][j], 0, 0, 0);
    }
    __syncthreads();
  }

  // epilogue: D layout col = lane&15, row = (lane>>4)*4 + reg  [m89-verified]
#pragma unroll
  for (int i = 0; i < 4; ++i) {
#pragma unroll
    for (int j = 0; j < 4; ++j) {
      int col = n0 + wn + j * 16 + lr;
      float bb = bias[col];
#pragma unroll
      for (int ii = 0; ii < 4; ++ii) {
        int row = m0 + wm + i * 16 + lg * 4 + ii;
        float v = acc[i][j][ii];
        if (MODE == 2) {
          ((float*)outp)[(size_t)row * D_MODEL + col] = v + bb;
        } else {
          v = (v + bb) * scale;
          int s = row >> 1, b2 = row & 1, h = col >> 6, d = col & 63;
          if (MODE == 0)
            ((bf16_t*)outp)[(((size_t)(b2 * HEADS + h) * SEQ) + s) * D_K + d] = (bf16_t)v;
          else
            ((bf16_t*)outp)[(((size_t)(b2 * HEADS + h) * D_K) + d) * SEQ + s] = (bf16_t)v;
        }
      }
    }
  }
}

// ------------------------------------------------------------------
// Flash attention with relative-position bias, TRANSPOSED-score form.
// grid = (SEQ/64, B*H). 4 waves, each owns 16 q-rows. K-tiles of 64.
// Q pre-scaled by 1/8 in projection. bias[q,k] = tbl[q - k + 2047] per head.
//
// QK^T swapped:  S^T = mfma(A=K_frag, B=Q_frag)
//   lane holds col q = w*16 + (l&15), rows k = kt + c*16 + (l>>4)*4 + i.
//   -> softmax row state (m, l, alpha) is PER-LANE for the lane's own q.
// PV swapped:    O^T = mfma(A=V_frag, B=P_frag)
//   output col = lane's own q -> alpha rescale & 1/l normalize lane-local.
// Only cross-lane traffic: 2 chained shfl_xor per tile (shared max) +
// the P LDS bounce (4x ds_write_b64 / 2x ds_read_b128 per lane).
// ------------------------------------------------------------------
#define TBL_N 2111
#define LDP 72  // P tile padded stride (bf16 elems)

__global__ __launch_bounds__(256) void attn_kernel(const bf16_t* __restrict__ Qa,
                                                   const bf16_t* __restrict__ Ka,
                                                   const bf16_t* __restrict__ Vt,
                                                   const float* __restrict__ rel,
                                                   bf16_t* __restrict__ ctx) {
  __shared__ float tbl[TBL_N + 1];
  __shared__ __align__(16) bf16_t p_lds[4][16 * LDP];  // per-wave P tile [q16][k64]

  const int qb = blockIdx.x, bh = blockIdx.y;
  const int h = bh & (HEADS - 1);
  const int b2 = bh >> 4;
  const int qbase = qb * 64;
  const int t = threadIdx.x, w = t >> 6, l = t & 63, lr = l & 15, lg = l >> 4;

  for (int j = t; j < TBL_N; j += 256) tbl[j] = rel[(qbase + j) * HEADS + h];
  __syncthreads();

  const bf16_t* Qbh = Qa + (size_t)bh * SEQ * D_K;
  const bf16_t* Kbh = Ka + (size_t)bh * SEQ * D_K;
  const bf16_t* Vbh = Vt + (size_t)bh * D_K * SEQ;

  const int qloc = w * 16 + lr;  // this lane's q (block-local)

  // Q as B-operand: lane holds col q=qloc, d = kk*32 + lg*8 + e
  bf16x8 qf[2];
#pragma unroll
  for (int kk = 0; kk < 2; ++kk)
    qf[kk] = *(const bf16x8*)(&Qbh[(size_t)(qbase + qloc) * D_K + kk * 32 + lg * 8]);

  float m_run = -3.0e38f, l_run = 0.f;
  f32x4 acc_o[4] = {};  // acc_o[c][ii] = O[d = c*16 + lg*4 + ii][q = qloc]

  bf16_t* pw = p_lds[w];

  for (int kt = 0; kt < SEQ; kt += 64) {
    // ---- S^T tile: sc[c][i] = S[k = kt + c*16 + lg*4 + i][q = qloc] ----
    f32x4 sc[4];
#pragma unroll
    for (int c = 0; c < 4; ++c) {
      f32x4 z = {};
#pragma unroll
      for (int kk = 0; kk < 2; ++kk) {
        bf16x8 kf = *(const bf16x8*)(&Kbh[(size_t)(kt + c * 16 + lr) * D_K + kk * 32 + lg * 8]);
        z = __builtin_amdgcn_mfma_f32_16x16x32_bf16(kf, qf[kk], z, 0, 0, 0);
      }
      sc[c] = z;
    }
    // ---- + bias (per-lane gather), in-lane max ----
    float cmax[4];
#pragma unroll
    for (int c = 0; c < 4; ++c) {
      int jb = qloc - (kt + c * 16 + lg * 4) + 2047;  // tbl idx for i=0 (desc. in i)
#pragma unroll
      for (int i = 0; i < 4; ++i) sc[c][i] += tbl[jb - i];
      cmax[c] = fmaxf(fmaxf(sc[c][0], sc[c][1]), fmaxf(sc[c][2], sc[c][3]));
    }
    float mt = fmaxf(fmaxf(cmax[0], cmax[1]), fmaxf(cmax[2], cmax[3]));
    // ---- share max across the 4 lanes holding this q (lg groups) ----
    mt = fmaxf(mt, __shfl_xor(mt, 16));
    mt = fmaxf(mt, __shfl_xor(mt, 32));
    float m_new = fmaxf(m_run, mt);
    float alpha = __expf(m_run - m_new);
    m_run = m_new;

    // ---- P = exp(s - m) -> bf16, partial denom in-lane, store b64 to LDS ----
    float vs = 0.f;
#pragma unroll
    for (int c = 0; c < 4; ++c) {
      bf16x4 pv;
#pragma unroll
      for (int i = 0; i < 4; ++i) {
        float p = __expf(sc[c][i] - m_new);
        bf16_t pb = (bf16_t)p;
        pv[i] = pb;
        vs += (float)pb;  // denominator consistent with bf16 numerator
      }
      *(bf16x4*)(&pw[lr * LDP + c * 16 + lg * 4]) = pv;
    }
    l_run = l_run * alpha + vs;

    // ---- rescale O (lane-local alpha) ----
#pragma unroll
    for (int c = 0; c < 4; ++c)
#pragma unroll
      for (int ii = 0; ii < 4; ++ii) acc_o[c][ii] *= alpha;

    // ---- PV: O^T += V^T_frag x P_frag  (compiler inserts lgkmcnt for pw dep) ----
#pragma unroll
    for (int kk = 0; kk < 2; ++kk) {
      bf16x8 pa = *(const bf16x8*)(&pw[lr * LDP + kk * 32 + lg * 8]);
#pragma unroll
      for (int c = 0; c < 4; ++c) {
        bf16x8 vf = *(const bf16x8*)(&Vbh[(size_t)(c * 16 + lr) * SEQ + kt + kk * 32 + lg * 8]);
        acc_o[c] = __builtin_amdgcn_mfma_f32_16x16x32_bf16(vf, pa, acc_o[c], 0, 0, 0);
      }
    }
  }

  // ---- final denominator: sum the 4 per-lane partials of this q ----
  float ls = l_run + __shfl_xor(l_run, 16);
  ls += __shfl_xor(ls, 32);
  float inv = 1.0f / ls;

  // ---- write ctx[m=(s,b)][h*64+d] bf16; lane owns q=qloc, d = c*16+lg*4+ii ----
  int qg = qbase + qloc;
  size_t base = ((size_t)qg * BATCH + b2) * D_MODEL + h * D_K;
#pragma unroll
  for (int c = 0; c < 4; ++c) {
    bf16x4 ov;
#pragma unroll
    for (int ii = 0; ii < 4; ++ii) ov[ii] = (bf16_t)(acc_o[c][ii] * inv);
    *(bf16x4*)(&ctx[base + c * 16 + lg * 4]) = ov;
  }
}

// ------------------------------------------------------------------
extern "C" void kernel_launch(void* const* d_in, const int* in_sizes, int n_in,
                              void* d_out, int out_size, void* d_ws, size_t ws_size,
                              hipStream_t stream) {
  const float* query = (const float*)d_in[0];
  const float* key_i = (const float*)d_in[1];
  const float* value = (const float*)d_in[2];
  const float* Wq = (const float*)d_in[3];
  const float* bq = (const float*)d_in[4];
  const float* Wk = (const float*)d_in[5];
  const float* bk = (const float*)d_in[6];
  const float* Wv = (const float*)d_in[7];
  const float* bv = (const float*)d_in[8];
  const float* Wo = (const float*)d_in[9];
  const float* bo = (const float*)d_in[10];
  const float* rel = (const float*)d_in[11];
  float* out = (float*)d_out;

  char* ws = (char*)d_ws;
  size_t off = 0;
  auto alloc = [&](size_t bytes) {
    char* p = ws + off;
    off = (off + bytes + 255) & ~(size_t)255;
    return p;
  };
  const size_t nIn = (size_t)MTOT * D_MODEL;   // 4,194,304
  const size_t nW = (size_t)D_MODEL * D_MODEL; // 1,048,576

  bf16_t* Xq = (bf16_t*)alloc(nIn * 2);
  bf16_t* Xk = (bf16_t*)alloc(nIn * 2);
  bf16_t* Xv = (bf16_t*)alloc(nIn * 2);
  bf16_t* Wqb = (bf16_t*)alloc(nW * 2);
  bf16_t* Wkb = (bf16_t*)alloc(nW * 2);
  bf16_t* Wvb = (bf16_t*)alloc(nW * 2);
  bf16_t* Wob = (bf16_t*)alloc(nW * 2);
  bf16_t* qa = (bf16_t*)alloc(nIn * 2);   // [B,H,S,64]
  bf16_t* ka = (bf16_t*)alloc(nIn * 2);   // [B,H,S,64]
  bf16_t* vt = (bf16_t*)alloc(nIn * 2);   // [B,H,64,S]
  bf16_t* ctx = (bf16_t*)alloc(nIn * 2);  // [M,1024]

  cvt_kernel<<<nIn / 2048, 256, 0, stream>>>(query, Xq, (int)nIn);
  cvt_kernel<<<nIn / 2048, 256, 0, stream>>>(key_i, Xk, (int)nIn);
  cvt_kernel<<<nIn / 2048, 256, 0, stream>>>(value, Xv, (int)nIn);
  cvt_kernel<<<nW / 2048, 256, 0, stream>>>(Wq, Wqb, (int)nW);
  cvt_kernel<<<nW / 2048, 256, 0, stream>>>(Wk, Wkb, (int)nW);
  cvt_kernel<<<nW / 2048, 256, 0, stream>>>(Wv, Wvb, (int)nW);
  cvt_kernel<<<nW / 2048, 256, 0, stream>>>(Wo, Wob, (int)nW);

  dim3 gg(D_MODEL / 128, MTOT / 128);
  gemm_bt<0><<<gg, 256, 0, stream>>>(Xq, Wqb, bq, qa, QSCALE);
  gemm_bt<0><<<gg, 256, 0, stream>>>(Xk, Wkb, bk, ka, 1.0f);
  gemm_bt<1><<<gg, 256, 0, stream>>>(Xv, Wvb, bv, vt, 1.0f);

  dim3 ga(SEQ / 64, BATCH * HEADS);
  attn_kernel<<<ga, 256, 0, stream>>>(qa, ka, vt, rel, ctx);

  gemm_bt<2><<<gg, 256, 0, stream>>>(ctx, Wob, bo, out, 1.0f);
}

// Round 3
// 190.044 us; speedup vs baseline: 1.8668x; 1.8396x over previous
//
#include <hip/hip_runtime.h>
#include <hip/hip_bf16.h>

typedef __bf16 bf16_t;
typedef __bf16 bf16x8 __attribute__((ext_vector_type(8)));
typedef __bf16 bf16x4 __attribute__((ext_vector_type(4)));
typedef float f32x4 __attribute__((ext_vector_type(4)));

#define D_MODEL 1024
#define HEADS 16
#define D_K 64
#define SEQ 2048
#define BATCH 2
#define MTOT (SEQ * BATCH) /* 4096 */
#define QSCALE 0.125f

// async global->LDS, 16B per lane; LDS dest is wave-uniform base + lane*16
#define GLDS16(g, l)                                                        \
  __builtin_amdgcn_global_load_lds(                                        \
      (const __attribute__((address_space(1))) unsigned int*)(g),          \
      (__attribute__((address_space(3))) unsigned int*)(l), 16, 0, 0)

// ------------------------------------------------------------------
// fp32 -> bf16 convert (vectorized, 8 elems/thread)
// ------------------------------------------------------------------
__global__ __launch_bounds__(256) void cvt_kernel(const float* __restrict__ src,
                                                  bf16_t* __restrict__ dst, int n) {
  int i = (blockIdx.x * 256 + threadIdx.x) * 8;
  if (i >= n) return;
  float4 a = *(const float4*)(src + i);
  float4 b = *(const float4*)(src + i + 4);
  bf16x8 v;
  v[0] = (bf16_t)a.x; v[1] = (bf16_t)a.y; v[2] = (bf16_t)a.z; v[3] = (bf16_t)a.w;
  v[4] = (bf16_t)b.x; v[5] = (bf16_t)b.y; v[6] = (bf16_t)b.z; v[7] = (bf16_t)b.w;
  *(bf16x8*)(dst + i) = v;
}

// ------------------------------------------------------------------
// GEMM: C[m][n] = X[m,:] . W[n,:] + bias[n]   (x @ W^T + b)
// MODE 0: bf16 out [B,H,S,64]; MODE 1: bf16 out [B,H,64,S]; MODE 2: fp32 [M,N]
// ------------------------------------------------------------------
#define GBK 64
#define LDK 72

template <int MODE>
__global__ __launch_bounds__(256) void gemm_bt(const bf16_t* __restrict__ X,
                                               const bf16_t* __restrict__ W,
                                               const float* __restrict__ bias,
                                               void* __restrict__ outp, float scale) {
  __shared__ __align__(16) bf16_t As[128 * LDK];
  __shared__ __align__(16) bf16_t Bs[128 * LDK];
  const int t = threadIdx.x;
  const int m0 = blockIdx.y * 128, n0 = blockIdx.x * 128;
  const int w = t >> 6, l = t & 63, lr = l & 15, lg = l >> 4;
  const int wm = (w >> 1) * 64, wn = (w & 1) * 64;

  f32x4 acc[4][4] = {};

  for (int kt = 0; kt < D_MODEL; kt += GBK) {
#pragma unroll
    for (int p = 0; p < 4; ++p) {
      int id = p * 256 + t;
      int row = id >> 3, ck = (id & 7) * 8;
      *(int4*)(&As[row * LDK + ck]) = *(const int4*)(&X[(size_t)(m0 + row) * D_MODEL + kt + ck]);
      *(int4*)(&Bs[row * LDK + ck]) = *(const int4*)(&W[(size_t)(n0 + row) * D_MODEL + kt + ck]);
    }
    __syncthreads();
#pragma unroll
    for (int kk = 0; kk < 2; ++kk) {
      bf16x8 a[4], b[4];
#pragma unroll
      for (int i = 0; i < 4; ++i)
        a[i] = *(const bf16x8*)(&As[(wm + i * 16 + lr) * LDK + kk * 32 + lg * 8]);
#pragma unroll
      for (int j = 0; j < 4; ++j)
        b[j] = *(const bf16x8*)(&Bs[(wn + j * 16 + lr) * LDK + kk * 32 + lg * 8]);
#pragma unroll
      for (int i = 0; i < 4; ++i)
#pragma unroll
        for (int j = 0; j < 4; ++j)
          acc[i][j] = __builtin_amdgcn_mfma_f32_16x16x32_bf16(a[i], b[j], acc[i][j], 0, 0, 0);
    }
    __syncthreads();
  }

#pragma unroll
  for (int i = 0; i < 4; ++i) {
#pragma unroll
    for (int j = 0; j < 4; ++j) {
      int col = n0 + wn + j * 16 + lr;
      float bb = bias[col];
#pragma unroll
      for (int ii = 0; ii < 4; ++ii) {
        int row = m0 + wm + i * 16 + lg * 4 + ii;
        float v = acc[i][j][ii];
        if (MODE == 2) {
          ((float*)outp)[(size_t)row * D_MODEL + col] = v + bb;
        } else {
          v = (v + bb) * scale;
          int s = row >> 1, b2 = row & 1, h = col >> 6, d = col & 63;
          if (MODE == 0)
            ((bf16_t*)outp)[(((size_t)(b2 * HEADS + h) * SEQ) + s) * D_K + d] = (bf16_t)v;
          else
            ((bf16_t*)outp)[(((size_t)(b2 * HEADS + h) * D_K) + d) * SEQ + s] = (bf16_t)v;
        }
      }
    }
  }
}

// ------------------------------------------------------------------
// Flash attention, transposed-score form, LDS-staged K/V.
// 512 threads = 8 waves, each owns 16 q of a 128-q block. K-tiles of 64.
// K/V staged once per block via global_load_lds (dbuf, 1 barrier/tile).
// LDS tiles are [64 rows][128 B]; reads XOR-swizzled (byte ^= (row&7)<<4),
// global source column pre-swizzled so the linear LDS dest matches (rule 21).
// ------------------------------------------------------------------
#define QBLK 128
#define KVBLK 64
#define NT (SEQ / KVBLK)
#define TBL_N 2175
#define LDP 72

__global__ __launch_bounds__(512, 4) void attn_kernel(const bf16_t* __restrict__ Qa,
                                                      const bf16_t* __restrict__ Ka,
                                                      const bf16_t* __restrict__ Vt,
                                                      const float* __restrict__ rel,
                                                      bf16_t* __restrict__ ctx) {
  __shared__ float tbl[TBL_N + 1];
  __shared__ __align__(16) bf16_t ks[2][KVBLK * 64];   // [k-local][d], swizzled
  __shared__ __align__(16) bf16_t vs[2][KVBLK * 64];   // [d][k-local], swizzled
  __shared__ __align__(16) bf16_t p_lds[8][16 * LDP];  // per-wave P [q16][k64]

  // bijective XCD swizzle: 512 blocks -> each XCD gets 64 consecutive (bh-major)
  const int f = blockIdx.x;
  const int nf = (f & 7) * 64 + (f >> 3);
  const int qb = nf & 15, bh = nf >> 4;
  const int h = bh & (HEADS - 1), b2 = bh >> 4;
  const int qbase = qb * QBLK;
  const int t = threadIdx.x, w = t >> 6, l = t & 63, lr = l & 15, lg = l >> 4;

  const bf16_t* Qbh = Qa + (size_t)bh * SEQ * D_K;
  const bf16_t* Kbh = Ka + (size_t)bh * SEQ * D_K;
  const bf16_t* Vbh = Vt + (size_t)bh * D_K * SEQ;

  // staging geometry: thread t writes 16B chunk #t of the 8KB tile.
  // phys chunk (row=t>>3, col16'=t&7) must hold source col16 = col16' ^ (row&7).
  const int srow = t >> 3;                          // 0..63
  const int scol = (((t & 7) ^ (srow & 7)) << 3);   // source col, elems
  const int sldsoff = w * 512;                      // wave-uniform, elems

  for (int j = t; j < TBL_N; j += 512) tbl[j] = rel[(size_t)(qbase + j) * HEADS + h];

  const int qloc = w * 16 + lr;  // this lane's q (block-local)
  bf16x8 qf[2];
#pragma unroll
  for (int kk = 0; kk < 2; ++kk)
    qf[kk] = *(const bf16x8*)(&Qbh[(size_t)(qbase + qloc) * D_K + kk * 32 + lg * 8]);

  // prologue: stage tile 0
  GLDS16(Kbh + (size_t)srow * D_K + scol, ks[0] + sldsoff);
  GLDS16(Vbh + (size_t)srow * SEQ + scol, vs[0] + sldsoff);
  __syncthreads();  // drains vmcnt + covers tbl

  float m_run = -3.0e38f, l_run = 0.f;
  f32x4 acc_o[4] = {};  // acc_o[c][ii] = O[d = c*16 + lg*4 + ii][q = qloc]
  bf16_t* pw = p_lds[w];
  const int sw = (lr & 7) << 4;  // read-side XOR (row&7 == lr&7 since c*16%8==0)

  for (int it = 0; it < NT; ++it) {
    const int cur = it & 1;
    const int kt = it * KVBLK;
    if (it + 1 < NT) {  // stage next tile into other buffer (async, lands by barrier)
      const int ktn = kt + KVBLK;
      GLDS16(Kbh + (size_t)(ktn + srow) * D_K + scol, ks[cur ^ 1] + sldsoff);
      GLDS16(Vbh + (size_t)srow * SEQ + ktn + scol, vs[cur ^ 1] + sldsoff);
    }
    const char* Kc = (const char*)ks[cur];
    const char* Vc = (const char*)vs[cur];

    // ---- S^T tile: sc[c][i] = S[k = kt + c*16 + lg*4 + i][q = qloc] ----
    f32x4 sc[4];
#pragma unroll
    for (int c = 0; c < 4; ++c) {
      f32x4 z = {};
#pragma unroll
      for (int kk = 0; kk < 2; ++kk) {
        bf16x8 kf = *(const bf16x8*)(Kc + (c * 16 + lr) * 128 + ((kk * 64 + lg * 16) ^ sw));
        z = __builtin_amdgcn_mfma_f32_16x16x32_bf16(kf, qf[kk], z, 0, 0, 0);
      }
      sc[c] = z;
    }
    // ---- + bias, in-lane max ----
    float cmax[4];
#pragma unroll
    for (int c = 0; c < 4; ++c) {
      int jb = qloc - (kt + c * 16 + lg * 4) + 2047;
#pragma unroll
      for (int i = 0; i < 4; ++i) sc[c][i] += tbl[jb - i];
      cmax[c] = fmaxf(fmaxf(sc[c][0], sc[c][1]), fmaxf(sc[c][2], sc[c][3]));
    }
    float mt = fmaxf(fmaxf(cmax[0], cmax[1]), fmaxf(cmax[2], cmax[3]));
    mt = fmaxf(mt, __shfl_xor(mt, 16));
    mt = fmaxf(mt, __shfl_xor(mt, 32));
    float m_new = fmaxf(m_run, mt);
    float alpha = __expf(m_run - m_new);
    m_run = m_new;

    // ---- P = exp(s - m) -> bf16, partial denom, b64 store to LDS ----
    float vsum = 0.f;
#pragma unroll
    for (int c = 0; c < 4; ++c) {
      bf16x4 pv;
#pragma unroll
      for (int i = 0; i < 4; ++i) {
        float p = __expf(sc[c][i] - m_new);
        bf16_t pb = (bf16_t)p;
        pv[i] = pb;
        vsum += (float)pb;
      }
      *(bf16x4*)(&pw[lr * LDP + c * 16 + lg * 4]) = pv;
    }
    l_run = l_run * alpha + vsum;

    // ---- rescale O ----
#pragma unroll
    for (int c = 0; c < 4; ++c)
#pragma unroll
      for (int ii = 0; ii < 4; ++ii) acc_o[c][ii] *= alpha;

    // ---- PV: O^T += V^T_frag x P_frag ----
#pragma unroll
    for (int kk = 0; kk < 2; ++kk) {
      bf16x8 pa = *(const bf16x8*)(&pw[lr * LDP + kk * 32 + lg * 8]);
#pragma unroll
      for (int c = 0; c < 4; ++c) {
        bf16x8 vf = *(const bf16x8*)(Vc + (c * 16 + lr) * 128 + ((kk * 64 + lg * 16) ^ sw));
        acc_o[c] = __builtin_amdgcn_mfma_f32_16x16x32_bf16(vf, pa, acc_o[c], 0, 0, 0);
      }
    }
    __syncthreads();  // stage(it+1) landed; all waves done reading cur
  }

  // ---- final denominator across the 4 lane-groups of this q ----
  float ls = l_run + __shfl_xor(l_run, 16);
  ls += __shfl_xor(ls, 32);
  float inv = 1.0f / ls;

  int qg = qbase + qloc;
  size_t base = ((size_t)qg * BATCH + b2) * D_MODEL + h * D_K;
#pragma unroll
  for (int c = 0; c < 4; ++c) {
    bf16x4 ov;
#pragma unroll
    for (int ii = 0; ii < 4; ++ii) ov[ii] = (bf16_t)(acc_o[c][ii] * inv);
    *(bf16x4*)(&ctx[base + c * 16 + lg * 4]) = ov;
  }
}

// ------------------------------------------------------------------
extern "C" void kernel_launch(void* const* d_in, const int* in_sizes, int n_in,
                              void* d_out, int out_size, void* d_ws, size_t ws_size,
                              hipStream_t stream) {
  const float* query = (const float*)d_in[0];
  const float* key_i = (const float*)d_in[1];
  const float* value = (const float*)d_in[2];
  const float* Wq = (const float*)d_in[3];
  const float* bq = (const float*)d_in[4];
  const float* Wk = (const float*)d_in[5];
  const float* bk = (const float*)d_in[6];
  const float* Wv = (const float*)d_in[7];
  const float* bv = (const float*)d_in[8];
  const float* Wo = (const float*)d_in[9];
  const float* bo = (const float*)d_in[10];
  const float* rel = (const float*)d_in[11];
  float* out = (float*)d_out;

  char* ws = (char*)d_ws;
  size_t off = 0;
  auto alloc = [&](size_t bytes) {
    char* p = ws + off;
    off = (off + bytes + 255) & ~(size_t)255;
    return p;
  };
  const size_t nIn = (size_t)MTOT * D_MODEL;
  const size_t nW = (size_t)D_MODEL * D_MODEL;

  bf16_t* Xq = (bf16_t*)alloc(nIn * 2);
  bf16_t* Xk = (bf16_t*)alloc(nIn * 2);
  bf16_t* Xv = (bf16_t*)alloc(nIn * 2);
  bf16_t* Wqb = (bf16_t*)alloc(nW * 2);
  bf16_t* Wkb = (bf16_t*)alloc(nW * 2);
  bf16_t* Wvb = (bf16_t*)alloc(nW * 2);
  bf16_t* Wob = (bf16_t*)alloc(nW * 2);
  bf16_t* qa = (bf16_t*)alloc(nIn * 2);   // [B,H,S,64]
  bf16_t* ka = (bf16_t*)alloc(nIn * 2);   // [B,H,S,64]
  bf16_t* vt = (bf16_t*)alloc(nIn * 2);   // [B,H,64,S]
  bf16_t* ctx = (bf16_t*)alloc(nIn * 2);  // [M,1024]

  cvt_kernel<<<nIn / 2048, 256, 0, stream>>>(query, Xq, (int)nIn);
  cvt_kernel<<<nIn / 2048, 256, 0, stream>>>(key_i, Xk, (int)nIn);
  cvt_kernel<<<nIn / 2048, 256, 0, stream>>>(value, Xv, (int)nIn);
  cvt_kernel<<<nW / 2048, 256, 0, stream>>>(Wq, Wqb, (int)nW);
  cvt_kernel<<<nW / 2048, 256, 0, stream>>>(Wk, Wkb, (int)nW);
  cvt_kernel<<<nW / 2048, 256, 0, stream>>>(Wv, Wvb, (int)nW);
  cvt_kernel<<<nW / 2048, 256, 0, stream>>>(Wo, Wob, (int)nW);

  dim3 gg(D_MODEL / 128, MTOT / 128);
  gemm_bt<0><<<gg, 256, 0, stream>>>(Xq, Wqb, bq, qa, QSCALE);
  gemm_bt<0><<<gg, 256, 0, stream>>>(Xk, Wkb, bk, ka, 1.0f);
  gemm_bt<1><<<gg, 256, 0, stream>>>(Xv, Wvb, bv, vt, 1.0f);

  attn_kernel<<<dim3(512), 512, 0, stream>>>(qa, ka, vt, rel, ctx);

  gemm_bt<2><<<gg, 256, 0, stream>>>(ctx, Wob, bo, out, 1.0f);
}

// Round 4
// 174.385 us; speedup vs baseline: 2.0344x; 1.0898x over previous
//
#include <hip/hip_runtime.h>
#include <hip/hip_bf16.h>

typedef __bf16 bf16_t;
typedef __bf16 bf16x8 __attribute__((ext_vector_type(8)));
typedef __bf16 bf16x4 __attribute__((ext_vector_type(4)));
typedef float f32x4 __attribute__((ext_vector_type(4)));

#define D_MODEL 1024
#define HEADS 16
#define D_K 64
#define SEQ 2048
#define BATCH 2
#define MTOT (SEQ * BATCH) /* 4096 */
#define LOG2E 1.4426950408889634f
#define QSCALE (0.125f * LOG2E) /* fold softmax scale AND log2e into Q */

// async global->LDS, 16B per lane; LDS dest = wave-uniform base + lane*16
#define GLDS16(g, l)                                                        \
  __builtin_amdgcn_global_load_lds(                                        \
      (const __attribute__((address_space(1))) unsigned int*)(g),          \
      (__attribute__((address_space(3))) unsigned int*)(l), 16, 0, 0)

// ------------------------------------------------------------------
// fp32 -> bf16 converts, batched (up to 4 arrays per launch)
// ------------------------------------------------------------------
__global__ __launch_bounds__(256) void cvt4_kernel(const float* s0, const float* s1,
                                                   const float* s2, const float* s3,
                                                   bf16_t* d0, bf16_t* d1, bf16_t* d2,
                                                   bf16_t* d3, int n) {
  const float* s; bf16_t* d;
  switch (blockIdx.y) {
    case 0: s = s0; d = d0; break;
    case 1: s = s1; d = d1; break;
    case 2: s = s2; d = d2; break;
    default: s = s3; d = d3; break;
  }
  int i = (blockIdx.x * 256 + threadIdx.x) * 8;
  if (i >= n) return;
  float4 a = *(const float4*)(s + i);
  float4 b = *(const float4*)(s + i + 4);
  bf16x8 v;
  v[0] = (bf16_t)a.x; v[1] = (bf16_t)a.y; v[2] = (bf16_t)a.z; v[3] = (bf16_t)a.w;
  v[4] = (bf16_t)b.x; v[5] = (bf16_t)b.y; v[6] = (bf16_t)b.z; v[7] = (bf16_t)b.w;
  *(bf16x8*)(d + i) = v;
}

// ------------------------------------------------------------------
// GEMM (m97 structure): C[m][n] = X[m,:].W[n,:] + bias[n]  (x @ W^T + b)
// 128x128 tile, BK=64, global_load_lds width-16 staging, linear LDS,
// single-buffered 2-barrier K-loop.
// MODE 0: bf16 out [B,H,S,64]; MODE 1: bf16 out [B,H,64,S]; MODE 2: fp32 [M,N]
// ------------------------------------------------------------------
template <int MODE>
__global__ __launch_bounds__(256) void gemm_bt(const bf16_t* __restrict__ X,
                                               const bf16_t* __restrict__ W,
                                               const float* __restrict__ bias,
                                               void* __restrict__ outp, float scale) {
  __shared__ __align__(16) bf16_t As[128 * 64];
  __shared__ __align__(16) bf16_t Bs[128 * 64];
  const int t = threadIdx.x;
  const int m0 = blockIdx.y * 128, n0 = blockIdx.x * 128;
  const int w = t >> 6, l = t & 63, lr = l & 15, lg = l >> 4;
  const int wm = (w >> 1) * 64, wn = (w & 1) * 64;

  f32x4 acc[4][4] = {};

  for (int kt = 0; kt < D_MODEL; kt += 64) {
    // stage 16KB A + 16KB B: chunk idx = p*256 + t -> row=idx>>3, col=(idx&7)*8
#pragma unroll
    for (int p = 0; p < 4; ++p) {
      int idx = p * 256 + t;
      int row = idx >> 3, ck = (idx & 7) * 8;
      int wb = (p * 256 + w * 64) * 8;  // wave-uniform LDS elem offset
      GLDS16(&X[(size_t)(m0 + row) * D_MODEL + kt + ck], As + wb);
      GLDS16(&W[(size_t)(n0 + row) * D_MODEL + kt + ck], Bs + wb);
    }
    __syncthreads();
#pragma unroll
    for (int kk = 0; kk < 2; ++kk) {
      bf16x8 a[4], b[4];
#pragma unroll
      for (int i = 0; i < 4; ++i)
        a[i] = *(const bf16x8*)(&As[(wm + i * 16 + lr) * 64 + kk * 32 + lg * 8]);
#pragma unroll
      for (int j = 0; j < 4; ++j)
        b[j] = *(const bf16x8*)(&Bs[(wn + j * 16 + lr) * 64 + kk * 32 + lg * 8]);
#pragma unroll
      for (int i = 0; i < 4; ++i)
#pragma unroll
        for (int j = 0; j < 4; ++j)
          acc[i][j] = __builtin_amdgcn_mfma_f32_16x16x32_bf16(a[i], b[j], acc[i][j], 0, 0, 0);
    }
    __syncthreads();
  }

  // epilogue: D layout col = lane&15, row = (lane>>4)*4 + reg  [m89-verified]
#pragma unroll
  for (int i = 0; i < 4; ++i) {
#pragma unroll
    for (int j = 0; j < 4; ++j) {
      int col = n0 + wn + j * 16 + lr;
      float bb = bias[col];
#pragma unroll
      for (int ii = 0; ii < 4; ++ii) {
        int row = m0 + wm + i * 16 + lg * 4 + ii;
        float v = acc[i][j][ii];
        if (MODE == 2) {
          ((float*)outp)[(size_t)row * D_MODEL + col] = v + bb;
        } else {
          v = (v + bb) * scale;
          int s = row >> 1, b2 = row & 1, h = col >> 6, d = col & 63;
          if (MODE == 0)
            ((bf16_t*)outp)[(((size_t)(b2 * HEADS + h) * SEQ) + s) * D_K + d] = (bf16_t)v;
          else
            ((bf16_t*)outp)[(((size_t)(b2 * HEADS + h) * D_K) + d) * SEQ + s] = (bf16_t)v;
        }
      }
    }
  }
}

// ------------------------------------------------------------------
// Flash attention, transposed-score form, LDS-staged K/V, NO-MAX softmax
// in the exp2 domain (log2e folded into Q scale and bias table).
//  - bias enters as the QK^T MFMA C-initializer (reversed table, vec reads)
//  - P = exp2(z) directly (single v_exp_f32)
//  - denominator l via ones-row MFMA (no per-lane adds, no final shuffles)
// 512 threads = 8 waves, 128 q/block, K-tiles of 64, dbuf global_load_lds.
// ------------------------------------------------------------------
#define QBLK 128
#define KVBLK 64
#define NT (SEQ / KVBLK)
#define TBL_N 2175
#define LDP 72

__global__ __launch_bounds__(512, 4) void attn_kernel(const bf16_t* __restrict__ Qa,
                                                      const bf16_t* __restrict__ Ka,
                                                      const bf16_t* __restrict__ Vt,
                                                      const float* __restrict__ rel,
                                                      bf16_t* __restrict__ ctx) {
  __shared__ float rbl[TBL_N + 1];                     // reversed, pre-scaled bias
  __shared__ __align__(16) bf16_t ks[2][KVBLK * 64];   // [k][d], chunk-swizzled
  __shared__ __align__(16) bf16_t vs[2][KVBLK * 64];   // [d][k], chunk-swizzled
  __shared__ __align__(16) bf16_t p_lds[8][16 * LDP];  // per-wave P [q16][k64]

  // bijective XCD swizzle: 512 blocks -> 64 consecutive per XCD (bh-major)
  const int f = blockIdx.x;
  const int nf = (f & 7) * 64 + (f >> 3);
  const int qb = nf & 15, bh = nf >> 4;
  const int h = bh & (HEADS - 1), b2 = bh >> 4;
  const int qbase = qb * QBLK;
  const int t = threadIdx.x, w = t >> 6, l = t & 63, lr = l & 15, lg = l >> 4;

  const bf16_t* Qbh = Qa + (size_t)bh * SEQ * D_K;
  const bf16_t* Kbh = Ka + (size_t)bh * SEQ * D_K;
  const bf16_t* Vbh = Vt + (size_t)bh * D_K * SEQ;

  // reversed bias table: rbl[j] = log2e * rel_head[qbase + 2174 - j]
  for (int j = t; j < TBL_N; j += 512)
    rbl[j] = LOG2E * rel[(size_t)(qbase + (TBL_N - 1) - j) * HEADS + h];

  // staging geometry: thread t -> 16B chunk (row=t>>3, physchunk=t&7);
  // phys chunk holds source col16 = (t&7) ^ (row&7)  (read-side XOR matches)
  const int srow = t >> 3;
  const int scol = (((t & 7) ^ (srow & 7)) << 3);
  const int sldsoff = w * 512;

  const int qloc = w * 16 + lr;  // this lane's q (block-local)
  bf16x8 qf[2];
#pragma unroll
  for (int kk = 0; kk < 2; ++kk)
    qf[kk] = *(const bf16x8*)(&Qbh[(size_t)(qbase + qloc) * D_K + kk * 32 + lg * 8]);

  bf16x8 ones;
#pragma unroll
  for (int e = 0; e < 8; ++e) ones[e] = (bf16_t)1.0f;

  GLDS16(Kbh + (size_t)srow * D_K + scol, ks[0] + sldsoff);
  GLDS16(Vbh + (size_t)srow * SEQ + scol, vs[0] + sldsoff);
  __syncthreads();  // drains staging vmcnt + covers rbl

  f32x4 acc_o[4] = {};  // acc_o[c][ii] = O[d = c*16 + lg*4 + ii][q = qloc]
  f32x4 l_acc = {};     // all entries = running denominator for q = qloc
  bf16_t* pw = p_lds[w];
  const int sw = (lr & 7) << 4;            // read-side chunk XOR
  const int roff = 127 - qloc + lg * 4;    // reversed-table base offset

  for (int it = 0; it < NT; ++it) {
    const int cur = it & 1;
    const int kt = it * KVBLK;
    if (it + 1 < NT) {
      const int ktn = kt + KVBLK;
      GLDS16(Kbh + (size_t)(ktn + srow) * D_K + scol, ks[cur ^ 1] + sldsoff);
      GLDS16(Vbh + (size_t)srow * SEQ + ktn + scol, vs[cur ^ 1] + sldsoff);
    }
    const char* Kc = (const char*)ks[cur];
    const char* Vc = (const char*)vs[cur];

    // ---- S^T tile in exp2 domain, bias as C-init ----
#pragma unroll
    for (int c = 0; c < 4; ++c) {
      const int r0 = roff + kt + c * 16;
      f32x4 z;
      z[0] = rbl[r0]; z[1] = rbl[r0 + 1]; z[2] = rbl[r0 + 2]; z[3] = rbl[r0 + 3];
#pragma unroll
      for (int kk = 0; kk < 2; ++kk) {
        bf16x8 kf = *(const bf16x8*)(Kc + (c * 16 + lr) * 128 + ((kk * 64 + lg * 16) ^ sw));
        z = __builtin_amdgcn_mfma_f32_16x16x32_bf16(kf, qf[kk], z, 0, 0, 0);
      }
      // ---- P = exp2(z) -> bf16, b64 store to LDS ----
      bf16x4 pv;
#pragma unroll
      for (int i = 0; i < 4; ++i) pv[i] = (bf16_t)__builtin_amdgcn_exp2f(z[i]);
      *(bf16x4*)(&pw[lr * LDP + c * 16 + lg * 4]) = pv;
    }

    // ---- PV: O^T += V^T_frag x P_frag ; l += ones x P_frag ----
#pragma unroll
    for (int kk = 0; kk < 2; ++kk) {
      bf16x8 pa = *(const bf16x8*)(&pw[lr * LDP + kk * 32 + lg * 8]);
      l_acc = __builtin_amdgcn_mfma_f32_16x16x32_bf16(ones, pa, l_acc, 0, 0, 0);
#pragma unroll
      for (int c = 0; c < 4; ++c) {
        bf16x8 vf = *(const bf16x8*)(Vc + (c * 16 + lr) * 128 + ((kk * 64 + lg * 16) ^ sw));
        acc_o[c] = __builtin_amdgcn_mfma_f32_16x16x32_bf16(vf, pa, acc_o[c], 0, 0, 0);
      }
    }
    __syncthreads();  // stage(it+1) landed; all waves done reading cur
  }

  const float inv = 1.0f / l_acc[0];

  int qg = qbase + qloc;
  size_t base = ((size_t)qg * BATCH + b2) * D_MODEL + h * D_K;
#pragma unroll
  for (int c = 0; c < 4; ++c) {
    bf16x4 ov;
#pragma unroll
    for (int ii = 0; ii < 4; ++ii) ov[ii] = (bf16_t)(acc_o[c][ii] * inv);
    *(bf16x4*)(&ctx[base + c * 16 + lg * 4]) = ov;
  }
}

// ------------------------------------------------------------------
extern "C" void kernel_launch(void* const* d_in, const int* in_sizes, int n_in,
                              void* d_out, int out_size, void* d_ws, size_t ws_size,
                              hipStream_t stream) {
  const float* query = (const float*)d_in[0];
  const float* key_i = (const float*)d_in[1];
  const float* value = (const float*)d_in[2];
  const float* Wq = (const float*)d_in[3];
  const float* bq = (const float*)d_in[4];
  const float* Wk = (const float*)d_in[5];
  const float* bk = (const float*)d_in[6];
  const float* Wv = (const float*)d_in[7];
  const float* bv = (const float*)d_in[8];
  const float* Wo = (const float*)d_in[9];
  const float* bo = (const float*)d_in[10];
  const float* rel = (const float*)d_in[11];
  float* out = (float*)d_out;

  char* ws = (char*)d_ws;
  size_t off = 0;
  auto alloc = [&](size_t bytes) {
    char* p = ws + off;
    off = (off + bytes + 255) & ~(size_t)255;
    return p;
  };
  const size_t nIn = (size_t)MTOT * D_MODEL;
  const size_t nW = (size_t)D_MODEL * D_MODEL;

  bf16_t* Xq = (bf16_t*)alloc(nIn * 2);
  bf16_t* Xk = (bf16_t*)alloc(nIn * 2);
  bf16_t* Xv = (bf16_t*)alloc(nIn * 2);
  bf16_t* Wqb = (bf16_t*)alloc(nW * 2);
  bf16_t* Wkb = (bf16_t*)alloc(nW * 2);
  bf16_t* Wvb = (bf16_t*)alloc(nW * 2);
  bf16_t* Wob = (bf16_t*)alloc(nW * 2);
  bf16_t* qa = (bf16_t*)alloc(nIn * 2);   // [B,H,S,64]
  bf16_t* ka = (bf16_t*)alloc(nIn * 2);   // [B,H,S,64]
  bf16_t* vt = (bf16_t*)alloc(nIn * 2);   // [B,H,64,S]
  bf16_t* ctx = (bf16_t*)alloc(nIn * 2);  // [M,1024]

  cvt4_kernel<<<dim3(nIn / 2048, 3), 256, 0, stream>>>(query, key_i, value, value, Xq, Xk,
                                                       Xv, Xv, (int)nIn);
  cvt4_kernel<<<dim3(nW / 2048, 4), 256, 0, stream>>>(Wq, Wk, Wv, Wo, Wqb, Wkb, Wvb, Wob,
                                                      (int)nW);

  dim3 gg(D_MODEL / 128, MTOT / 128);
  gemm_bt<0><<<gg, 256, 0, stream>>>(Xq, Wqb, bq, qa, QSCALE);
  gemm_bt<0><<<gg, 256, 0, stream>>>(Xk, Wkb, bk, ka, 1.0f);
  gemm_bt<1><<<gg, 256, 0, stream>>>(Xv, Wvb, bv, vt, 1.0f);

  attn_kernel<<<dim3(512), 512, 0, stream>>>(qa, ka, vt, rel, ctx);

  gemm_bt<2><<<gg, 256, 0, stream>>>(ctx, Wob, bo, out, 1.0f);
}

// Round 5
// 162.888 us; speedup vs baseline: 2.1780x; 1.0706x over previous
//
#include <hip/hip_runtime.h>
#include <hip/hip_bf16.h>

typedef __bf16 bf16_t;
typedef __bf16 bf16x8 __attribute__((ext_vector_type(8)));
typedef __bf16 bf16x4 __attribute__((ext_vector_type(4)));
typedef float f32x4 __attribute__((ext_vector_type(4)));

#define D_MODEL 1024
#define HEADS 16
#define D_K 64
#define SEQ 2048
#define BATCH 2
#define MTOT (SEQ * BATCH) /* 4096 */
#define LOG2E 1.4426950408889634f
#define QSCALE (0.125f * LOG2E) /* fold softmax scale AND log2e into Q */

// async global->LDS, 16B per lane; LDS dest = wave-uniform base + lane*16
#define GLDS16(g, l)                                                        \
  __builtin_amdgcn_global_load_lds(                                        \
      (const __attribute__((address_space(1))) unsigned int*)(g),          \
      (__attribute__((address_space(3))) unsigned int*)(l), 16, 0, 0)

// ------------------------------------------------------------------
// fp32 -> bf16 converts, batched (up to 4 arrays per launch)
// ------------------------------------------------------------------
__global__ __launch_bounds__(256) void cvt4_kernel(const float* s0, const float* s1,
                                                   const float* s2, const float* s3,
                                                   bf16_t* d0, bf16_t* d1, bf16_t* d2,
                                                   bf16_t* d3, int n) {
  const float* s; bf16_t* d;
  switch (blockIdx.y) {
    case 0: s = s0; d = d0; break;
    case 1: s = s1; d = d1; break;
    case 2: s = s2; d = d2; break;
    default: s = s3; d = d3; break;
  }
  int i = (blockIdx.x * 256 + threadIdx.x) * 8;
  if (i >= n) return;
  float4 a = *(const float4*)(s + i);
  float4 b = *(const float4*)(s + i + 4);
  bf16x8 v;
  v[0] = (bf16_t)a.x; v[1] = (bf16_t)a.y; v[2] = (bf16_t)a.z; v[3] = (bf16_t)a.w;
  v[4] = (bf16_t)b.x; v[5] = (bf16_t)b.y; v[6] = (bf16_t)b.z; v[7] = (bf16_t)b.w;
  *(bf16x8*)(d + i) = v;
}

// ------------------------------------------------------------------
// Fused QKV projection GEMM. Grid (24, 32): bx/8 selects segment
// (0=Q, 1=K, 2=V); each segment is an independent M=4096,N=1024,K=1024
// x @ W^T + b. 128x128 tile, BK=64, global_load_lds staging (m97 form).
// 768 blocks -> 3 blocks/CU -> 12 waves/CU.
// Q out: [B,H,S,64] * QSCALE; K out: [B,H,S,64]; V out: [B,H,64,S].
// ------------------------------------------------------------------
__global__ __launch_bounds__(256) void gemm_qkv(const bf16_t* __restrict__ Xq,
                                                const bf16_t* __restrict__ Xk,
                                                const bf16_t* __restrict__ Xv,
                                                const bf16_t* __restrict__ Wqkv,
                                                const float* __restrict__ bq,
                                                const float* __restrict__ bk,
                                                const float* __restrict__ bv,
                                                bf16_t* __restrict__ qa,
                                                bf16_t* __restrict__ ka,
                                                bf16_t* __restrict__ vt) {
  __shared__ __align__(16) bf16_t As[128 * 64];
  __shared__ __align__(16) bf16_t Bs[128 * 64];
  const int t = threadIdx.x;
  const int seg = blockIdx.x >> 3;  // 0=Q 1=K 2=V
  const bf16_t* X = seg == 0 ? Xq : (seg == 1 ? Xk : Xv);
  const float* bias = seg == 0 ? bq : (seg == 1 ? bk : bv);
  const float scale = seg == 0 ? QSCALE : 1.0f;
  const int m0 = blockIdx.y * 128;
  const int n0g = blockIdx.x * 128;  // global col in [0,3072)
  const int w = t >> 6, l = t & 63, lr = l & 15, lg = l >> 4;
  const int wm = (w >> 1) * 64, wn = (w & 1) * 64;

  f32x4 acc[4][4] = {};

  for (int kt = 0; kt < D_MODEL; kt += 64) {
#pragma unroll
    for (int p = 0; p < 4; ++p) {
      int idx = p * 256 + t;
      int row = idx >> 3, ck = (idx & 7) * 8;
      int wb = (p * 256 + w * 64) * 8;  // wave-uniform LDS elem offset
      GLDS16(&X[(size_t)(m0 + row) * D_MODEL + kt + ck], As + wb);
      GLDS16(&Wqkv[(size_t)(n0g + row) * D_MODEL + kt + ck], Bs + wb);
    }
    __syncthreads();
#pragma unroll
    for (int kk = 0; kk < 2; ++kk) {
      bf16x8 a[4], b[4];
#pragma unroll
      for (int i = 0; i < 4; ++i)
        a[i] = *(const bf16x8*)(&As[(wm + i * 16 + lr) * 64 + kk * 32 + lg * 8]);
#pragma unroll
      for (int j = 0; j < 4; ++j)
        b[j] = *(const bf16x8*)(&Bs[(wn + j * 16 + lr) * 64 + kk * 32 + lg * 8]);
#pragma unroll
      for (int i = 0; i < 4; ++i)
#pragma unroll
        for (int j = 0; j < 4; ++j)
          acc[i][j] = __builtin_amdgcn_mfma_f32_16x16x32_bf16(a[i], b[j], acc[i][j], 0, 0, 0);
    }
    __syncthreads();
  }

  // epilogue: D layout col = lane&15, row = (lane>>4)*4 + reg  [m89-verified]
#pragma unroll
  for (int i = 0; i < 4; ++i) {
#pragma unroll
    for (int j = 0; j < 4; ++j) {
      int lc = ((n0g + wn) & 1023) + j * 16 + lr;  // segment-local col
      float bb = bias[lc];
      int h = lc >> 6, d = lc & 63;
#pragma unroll
      for (int ii = 0; ii < 4; ++ii) {
        int row = m0 + wm + i * 16 + lg * 4 + ii;
        float v = (acc[i][j][ii] + bb) * scale;
        int s = row >> 1, b2 = row & 1;
        if (seg == 2)
          vt[(((size_t)(b2 * HEADS + h) * D_K) + d) * SEQ + s] = (bf16_t)v;
        else if (seg == 1)
          ka[(((size_t)(b2 * HEADS + h) * SEQ) + s) * D_K + d] = (bf16_t)v;
        else
          qa[(((size_t)(b2 * HEADS + h) * SEQ) + s) * D_K + d] = (bf16_t)v;
      }
    }
  }
}

// ------------------------------------------------------------------
// Output GEMM: out[m][n] = ctx[m,:].Wo[n,:] + bo[n], fp32 out.
// 128x128 tile but 512 threads / 8 waves (2x4), 2 waves/SIMD at 1 block/CU.
// ------------------------------------------------------------------
__global__ __launch_bounds__(512) void gemm_out(const bf16_t* __restrict__ X,
                                                const bf16_t* __restrict__ W,
                                                const float* __restrict__ bias,
                                                float* __restrict__ out) {
  __shared__ __align__(16) bf16_t As[128 * 64];
  __shared__ __align__(16) bf16_t Bs[128 * 64];
  const int t = threadIdx.x;
  const int m0 = blockIdx.y * 128, n0 = blockIdx.x * 128;
  const int w = t >> 6, l = t & 63, lr = l & 15, lg = l >> 4;
  const int wm = (w >> 2) * 64, wn = (w & 3) * 32;

  f32x4 acc[4][2] = {};

  for (int kt = 0; kt < D_MODEL; kt += 64) {
#pragma unroll
    for (int p = 0; p < 2; ++p) {
      int idx = p * 512 + t;
      int row = idx >> 3, ck = (idx & 7) * 8;
      int wb = (p * 512 + w * 64) * 8;  // wave-uniform LDS elem offset
      GLDS16(&X[(size_t)(m0 + row) * D_MODEL + kt + ck], As + wb);
      GLDS16(&W[(size_t)(n0 + row) * D_MODEL + kt + ck], Bs + wb);
    }
    __syncthreads();
#pragma unroll
    for (int kk = 0; kk < 2; ++kk) {
      bf16x8 a[4], b[2];
#pragma unroll
      for (int i = 0; i < 4; ++i)
        a[i] = *(const bf16x8*)(&As[(wm + i * 16 + lr) * 64 + kk * 32 + lg * 8]);
#pragma unroll
      for (int j = 0; j < 2; ++j)
        b[j] = *(const bf16x8*)(&Bs[(wn + j * 16 + lr) * 64 + kk * 32 + lg * 8]);
#pragma unroll
      for (int i = 0; i < 4; ++i)
#pragma unroll
        for (int j = 0; j < 2; ++j)
          acc[i][j] = __builtin_amdgcn_mfma_f32_16x16x32_bf16(a[i], b[j], acc[i][j], 0, 0, 0);
    }
    __syncthreads();
  }

#pragma unroll
  for (int i = 0; i < 4; ++i) {
#pragma unroll
    for (int j = 0; j < 2; ++j) {
      int col = n0 + wn + j * 16 + lr;
      float bb = bias[col];
#pragma unroll
      for (int ii = 0; ii < 4; ++ii) {
        int row = m0 + wm + i * 16 + lg * 4 + ii;
        out[(size_t)row * D_MODEL + col] = acc[i][j][ii] + bb;
      }
    }
  }
}

// ------------------------------------------------------------------
// Flash attention, transposed-score form, LDS-staged K/V, NO-MAX softmax
// in the exp2 domain (log2e folded into Q scale and bias table).
// 512 threads = 8 waves, 128 q/block, K-tiles of 64, dbuf global_load_lds.
// ------------------------------------------------------------------
#define QBLK 128
#define KVBLK 64
#define NT (SEQ / KVBLK)
#define TBL_N 2175
#define LDP 72

__global__ __launch_bounds__(512, 4) void attn_kernel(const bf16_t* __restrict__ Qa,
                                                      const bf16_t* __restrict__ Ka,
                                                      const bf16_t* __restrict__ Vt,
                                                      const float* __restrict__ rel,
                                                      bf16_t* __restrict__ ctx) {
  __shared__ float rbl[TBL_N + 1];                     // reversed, pre-scaled bias
  __shared__ __align__(16) bf16_t ks[2][KVBLK * 64];   // [k][d], chunk-swizzled
  __shared__ __align__(16) bf16_t vs[2][KVBLK * 64];   // [d][k], chunk-swizzled
  __shared__ __align__(16) bf16_t p_lds[8][16 * LDP];  // per-wave P [q16][k64]

  // bijective XCD swizzle: 512 blocks -> 64 consecutive per XCD (bh-major)
  const int f = blockIdx.x;
  const int nf = (f & 7) * 64 + (f >> 3);
  const int qb = nf & 15, bh = nf >> 4;
  const int h = bh & (HEADS - 1), b2 = bh >> 4;
  const int qbase = qb * QBLK;
  const int t = threadIdx.x, w = t >> 6, l = t & 63, lr = l & 15, lg = l >> 4;

  const bf16_t* Qbh = Qa + (size_t)bh * SEQ * D_K;
  const bf16_t* Kbh = Ka + (size_t)bh * SEQ * D_K;
  const bf16_t* Vbh = Vt + (size_t)bh * D_K * SEQ;

  // reversed bias table: rbl[j] = log2e * rel_head[qbase + 2174 - j]
  for (int j = t; j < TBL_N; j += 512)
    rbl[j] = LOG2E * rel[(size_t)(qbase + (TBL_N - 1) - j) * HEADS + h];

  // staging: thread t -> 16B chunk (row=t>>3, physchunk=t&7);
  // phys chunk holds source col16 = (t&7) ^ (row&7)  (read-side XOR matches)
  const int srow = t >> 3;
  const int scol = (((t & 7) ^ (srow & 7)) << 3);
  const int sldsoff = w * 512;

  const int qloc = w * 16 + lr;  // this lane's q (block-local)
  bf16x8 qf[2];
#pragma unroll
  for (int kk = 0; kk < 2; ++kk)
    qf[kk] = *(const bf16x8*)(&Qbh[(size_t)(qbase + qloc) * D_K + kk * 32 + lg * 8]);

  bf16x8 ones;
#pragma unroll
  for (int e = 0; e < 8; ++e) ones[e] = (bf16_t)1.0f;

  GLDS16(Kbh + (size_t)srow * D_K + scol, ks[0] + sldsoff);
  GLDS16(Vbh + (size_t)srow * SEQ + scol, vs[0] + sldsoff);
  __syncthreads();  // drains staging vmcnt + covers rbl

  f32x4 acc_o[4] = {};  // acc_o[c][ii] = O[d = c*16 + lg*4 + ii][q = qloc]
  f32x4 l_acc = {};     // all entries = running denominator for q = qloc
  bf16_t* pw = p_lds[w];
  const int sw = (lr & 7) << 4;          // read-side chunk XOR
  const int roff = 127 - qloc + lg * 4;  // reversed-table base offset

  for (int it = 0; it < NT; ++it) {
    const int cur = it & 1;
    const int kt = it * KVBLK;
    if (it + 1 < NT) {
      const int ktn = kt + KVBLK;
      GLDS16(Kbh + (size_t)(ktn + srow) * D_K + scol, ks[cur ^ 1] + sldsoff);
      GLDS16(Vbh + (size_t)srow * SEQ + ktn + scol, vs[cur ^ 1] + sldsoff);
    }
    const char* Kc = (const char*)ks[cur];
    const char* Vc = (const char*)vs[cur];

    // ---- S^T tile in exp2 domain, bias as C-init; P = exp2(z) ----
#pragma unroll
    for (int c = 0; c < 4; ++c) {
      const int r0 = roff + kt + c * 16;
      f32x4 z;
      z[0] = rbl[r0]; z[1] = rbl[r0 + 1]; z[2] = rbl[r0 + 2]; z[3] = rbl[r0 + 3];
#pragma unroll
      for (int kk = 0; kk < 2; ++kk) {
        bf16x8 kf = *(const bf16x8*)(Kc + (c * 16 + lr) * 128 + ((kk * 64 + lg * 16) ^ sw));
        z = __builtin_amdgcn_mfma_f32_16x16x32_bf16(kf, qf[kk], z, 0, 0, 0);
      }
      bf16x4 pv;
#pragma unroll
      for (int i = 0; i < 4; ++i) pv[i] = (bf16_t)__builtin_amdgcn_exp2f(z[i]);
      *(bf16x4*)(&pw[lr * LDP + c * 16 + lg * 4]) = pv;
    }

    // ---- PV: O^T += V^T_frag x P_frag ; l += ones x P_frag ----
    __builtin_amdgcn_s_setprio(1);
#pragma unroll
    for (int kk = 0; kk < 2; ++kk) {
      bf16x8 pa = *(const bf16x8*)(&pw[lr * LDP + kk * 32 + lg * 8]);
      l_acc = __builtin_amdgcn_mfma_f32_16x16x32_bf16(ones, pa, l_acc, 0, 0, 0);
#pragma unroll
      for (int c = 0; c < 4; ++c) {
        bf16x8 vf = *(const bf16x8*)(Vc + (c * 16 + lr) * 128 + ((kk * 64 + lg * 16) ^ sw));
        acc_o[c] = __builtin_amdgcn_mfma_f32_16x16x32_bf16(vf, pa, acc_o[c], 0, 0, 0);
      }
    }
    __builtin_amdgcn_s_setprio(0);
    __syncthreads();  // stage(it+1) landed; all waves done reading cur
  }

  const float inv = 1.0f / l_acc[0];

  int qg = qbase + qloc;
  size_t base = ((size_t)qg * BATCH + b2) * D_MODEL + h * D_K;
#pragma unroll
  for (int c = 0; c < 4; ++c) {
    bf16x4 ov;
#pragma unroll
    for (int ii = 0; ii < 4; ++ii) ov[ii] = (bf16_t)(acc_o[c][ii] * inv);
    *(bf16x4*)(&ctx[base + c * 16 + lg * 4]) = ov;
  }
}

// ------------------------------------------------------------------
extern "C" void kernel_launch(void* const* d_in, const int* in_sizes, int n_in,
                              void* d_out, int out_size, void* d_ws, size_t ws_size,
                              hipStream_t stream) {
  const float* query = (const float*)d_in[0];
  const float* key_i = (const float*)d_in[1];
  const float* value = (const float*)d_in[2];
  const float* Wq = (const float*)d_in[3];
  const float* bq = (const float*)d_in[4];
  const float* Wk = (const float*)d_in[5];
  const float* bk = (const float*)d_in[6];
  const float* Wv = (const float*)d_in[7];
  const float* bv = (const float*)d_in[8];
  const float* Wo = (const float*)d_in[9];
  const float* bo = (const float*)d_in[10];
  const float* rel = (const float*)d_in[11];
  float* out = (float*)d_out;

  char* ws = (char*)d_ws;
  size_t off = 0;
  auto alloc = [&](size_t bytes) {
    char* p = ws + off;
    off = (off + bytes + 255) & ~(size_t)255;
    return p;
  };
  const size_t nIn = (size_t)MTOT * D_MODEL;
  const size_t nW = (size_t)D_MODEL * D_MODEL;

  bf16_t* Xq = (bf16_t*)alloc(nIn * 2);
  bf16_t* Xk = (bf16_t*)alloc(nIn * 2);
  bf16_t* Xv = (bf16_t*)alloc(nIn * 2);
  bf16_t* Wqkv = (bf16_t*)alloc(3 * nW * 2);  // Wq | Wk | Wv rows, contiguous
  bf16_t* Wob = (bf16_t*)alloc(nW * 2);
  bf16_t* qa = (bf16_t*)alloc(nIn * 2);   // [B,H,S,64]
  bf16_t* ka = (bf16_t*)alloc(nIn * 2);   // [B,H,S,64]
  bf16_t* vt = (bf16_t*)alloc(nIn * 2);   // [B,H,64,S]
  bf16_t* ctx = (bf16_t*)alloc(nIn * 2);  // [M,1024]

  cvt4_kernel<<<dim3(nIn / 2048, 3), 256, 0, stream>>>(query, key_i, value, value, Xq, Xk,
                                                       Xv, Xv, (int)nIn);
  cvt4_kernel<<<dim3(nW / 2048, 4), 256, 0, stream>>>(Wq, Wk, Wv, Wo, Wqkv, Wqkv + nW,
                                                      Wqkv + 2 * nW, Wob, (int)nW);

  gemm_qkv<<<dim3(24, 32), 256, 0, stream>>>(Xq, Xk, Xv, Wqkv, bq, bk, bv, qa, ka, vt);

  attn_kernel<<<dim3(512), 512, 0, stream>>>(qa, ka, vt, rel, ctx);

  gemm_out<<<dim3(8, 32), 512, 0, stream>>>(ctx, Wob, bo, out);
}

// Round 6
// 141.821 us; speedup vs baseline: 2.5016x; 1.1485x over previous
//
#include <hip/hip_runtime.h>
#include <hip/hip_bf16.h>

typedef __bf16 bf16_t;
typedef __bf16 bf16x8 __attribute__((ext_vector_type(8)));
typedef __bf16 bf16x4 __attribute__((ext_vector_type(4)));
typedef float f32x4 __attribute__((ext_vector_type(4)));

#define D_MODEL 1024
#define HEADS 16
#define D_K 64
#define SEQ 2048
#define BATCH 2
#define MTOT (SEQ * BATCH) /* 4096 */
#define LOG2E 1.4426950408889634f
#define QSCALE (0.125f * LOG2E) /* fold softmax scale AND log2e into Q */

// async global->LDS, 16B per lane; LDS dest = wave-uniform base + lane*16
#define GLDS16(g, l)                                                        \
  __builtin_amdgcn_global_load_lds(                                        \
      (const __attribute__((address_space(1))) unsigned int*)(g),          \
      (__attribute__((address_space(3))) unsigned int*)(l), 16, 0, 0)

// ------------------------------------------------------------------
// fp32 -> bf16 converts, batched (up to 4 arrays per launch)
// ------------------------------------------------------------------
__global__ __launch_bounds__(256) void cvt4_kernel(const float* s0, const float* s1,
                                                   const float* s2, const float* s3,
                                                   bf16_t* d0, bf16_t* d1, bf16_t* d2,
                                                   bf16_t* d3, int n) {
  const float* s; bf16_t* d;
  switch (blockIdx.y) {
    case 0: s = s0; d = d0; break;
    case 1: s = s1; d = d1; break;
    case 2: s = s2; d = d2; break;
    default: s = s3; d = d3; break;
  }
  int i = (blockIdx.x * 256 + threadIdx.x) * 8;
  if (i >= n) return;
  float4 a = *(const float4*)(s + i);
  float4 b = *(const float4*)(s + i + 4);
  bf16x8 v;
  v[0] = (bf16_t)a.x; v[1] = (bf16_t)a.y; v[2] = (bf16_t)a.z; v[3] = (bf16_t)a.w;
  v[4] = (bf16_t)b.x; v[5] = (bf16_t)b.y; v[6] = (bf16_t)b.z; v[7] = (bf16_t)b.w;
  *(bf16x8*)(d + i) = v;
}

// ------------------------------------------------------------------
// Fused QKV projection GEMM. Flat grid of 768 blocks, decoded so XCD x
// (= blockIdx%8) owns row-panels {4x..4x+3} x all 24 col-blocks -> each
// X row-panel is L2-resident on exactly one XCD (kills HBM over-fetch).
// LDS tiles XOR-swizzled via pre-swizzled global source (rule 21 / T2):
// phys chunk (row, c) holds source chunk c^(row&7); reads XOR byte<<4.
// Q out: [B,H,S,64] * QSCALE; K out: [B,H,S,64]; V out: [B,H,64,S].
// ------------------------------------------------------------------
__global__ __launch_bounds__(256) void gemm_qkv(const bf16_t* __restrict__ Xq,
                                                const bf16_t* __restrict__ Xk,
                                                const bf16_t* __restrict__ Xv,
                                                const bf16_t* __restrict__ Wqkv,
                                                const float* __restrict__ bq,
                                                const float* __restrict__ bk,
                                                const float* __restrict__ bv,
                                                bf16_t* __restrict__ qa,
                                                bf16_t* __restrict__ ka,
                                                bf16_t* __restrict__ vt) {
  __shared__ __align__(16) bf16_t As[128 * 64];
  __shared__ __align__(16) bf16_t Bs[128 * 64];
  const int t = threadIdx.x;
  const int f = blockIdx.x;
  const int xcd = f & 7, fi = f >> 3;
  const int by = xcd * 4 + (fi & 3);  // row-panel, clustered per XCD
  const int bxi = fi >> 2;            // 0..23 col-block (seg-major)
  const int seg = bxi >> 3;           // 0=Q 1=K 2=V
  const bf16_t* X = seg == 0 ? Xq : (seg == 1 ? Xk : Xv);
  const float* bias = seg == 0 ? bq : (seg == 1 ? bk : bv);
  const float scale = seg == 0 ? QSCALE : 1.0f;
  const int m0 = by * 128;
  const int n0g = bxi * 128;  // global col in [0,3072)
  const int w = t >> 6, l = t & 63, lr = l & 15, lg = l >> 4;
  const int wm = (w >> 1) * 64, wn = (w & 1) * 64;

  f32x4 acc[4][4] = {};

  // staging geometry: chunk idx = p*256+t -> phys (row=idx>>3, c=idx&7);
  // source col chunk = c ^ (row&7)  (T2 pre-swizzled source)
  const int sx = (lr & 7) << 4;  // read-side XOR (row&7 == lr&7)

  for (int kt = 0; kt < D_MODEL; kt += 64) {
#pragma unroll
    for (int p = 0; p < 4; ++p) {
      int idx = p * 256 + t;
      int row = idx >> 3;
      int ck = (((idx & 7) ^ (row & 7)) << 3);
      int wb = (p * 256 + w * 64) * 8;  // wave-uniform LDS elem offset
      GLDS16(&X[(size_t)(m0 + row) * D_MODEL + kt + ck], As + wb);
      GLDS16(&Wqkv[(size_t)(n0g + row) * D_MODEL + kt + ck], Bs + wb);
    }
    __syncthreads();
#pragma unroll
    for (int kk = 0; kk < 2; ++kk) {
      bf16x8 a[4], b[4];
#pragma unroll
      for (int i = 0; i < 4; ++i)
        a[i] = *(const bf16x8*)((const char*)As + (wm + i * 16 + lr) * 128 +
                                ((kk * 64 + lg * 16) ^ sx));
#pragma unroll
      for (int j = 0; j < 4; ++j)
        b[j] = *(const bf16x8*)((const char*)Bs + (wn + j * 16 + lr) * 128 +
                                ((kk * 64 + lg * 16) ^ sx));
#pragma unroll
      for (int i = 0; i < 4; ++i)
#pragma unroll
        for (int j = 0; j < 4; ++j)
          acc[i][j] = __builtin_amdgcn_mfma_f32_16x16x32_bf16(a[i], b[j], acc[i][j], 0, 0, 0);
    }
    __syncthreads();
  }

  // epilogue: D layout col = lane&15, row = (lane>>4)*4 + reg  [m89-verified]
#pragma unroll
  for (int i = 0; i < 4; ++i) {
#pragma unroll
    for (int j = 0; j < 4; ++j) {
      int lc = ((n0g + wn) & 1023) + j * 16 + lr;  // segment-local col
      float bb = bias[lc];
      int h = lc >> 6, d = lc & 63;
#pragma unroll
      for (int ii = 0; ii < 4; ++ii) {
        int row = m0 + wm + i * 16 + lg * 4 + ii;
        float v = (acc[i][j][ii] + bb) * scale;
        int s = row >> 1, b2 = row & 1;
        if (seg == 2)
          vt[(((size_t)(b2 * HEADS + h) * D_K) + d) * SEQ + s] = (bf16_t)v;
        else if (seg == 1)
          ka[(((size_t)(b2 * HEADS + h) * SEQ) + s) * D_K + d] = (bf16_t)v;
        else
          qa[(((size_t)(b2 * HEADS + h) * SEQ) + s) * D_K + d] = (bf16_t)v;
      }
    }
  }
}

// ------------------------------------------------------------------
// Output GEMM: out[m][n] = ctx[m,:].Wo[n,:] + bo[n], fp32 out.
// 128x128 tile, 512 threads / 8 waves (2x4). Flat 256-block grid with
// the same XCD row-panel clustering + T2 LDS swizzle.
// ------------------------------------------------------------------
__global__ __launch_bounds__(512) void gemm_out(const bf16_t* __restrict__ X,
                                                const bf16_t* __restrict__ W,
                                                const float* __restrict__ bias,
                                                float* __restrict__ out) {
  __shared__ __align__(16) bf16_t As[128 * 64];
  __shared__ __align__(16) bf16_t Bs[128 * 64];
  const int t = threadIdx.x;
  const int f = blockIdx.x;
  const int xcd = f & 7, fi = f >> 3;
  const int by = xcd * 4 + (fi & 3);
  const int bx = fi >> 2;  // 0..7
  const int m0 = by * 128, n0 = bx * 128;
  const int w = t >> 6, l = t & 63, lr = l & 15, lg = l >> 4;
  const int wm = (w >> 2) * 64, wn = (w & 3) * 32;
  const int sx = (lr & 7) << 4;

  f32x4 acc[4][2] = {};

  for (int kt = 0; kt < D_MODEL; kt += 64) {
#pragma unroll
    for (int p = 0; p < 2; ++p) {
      int idx = p * 512 + t;
      int row = idx >> 3;
      int ck = (((idx & 7) ^ (row & 7)) << 3);
      int wb = (p * 512 + w * 64) * 8;  // wave-uniform LDS elem offset
      GLDS16(&X[(size_t)(m0 + row) * D_MODEL + kt + ck], As + wb);
      GLDS16(&W[(size_t)(n0 + row) * D_MODEL + kt + ck], Bs + wb);
    }
    __syncthreads();
#pragma unroll
    for (int kk = 0; kk < 2; ++kk) {
      bf16x8 a[4], b[2];
#pragma unroll
      for (int i = 0; i < 4; ++i)
        a[i] = *(const bf16x8*)((const char*)As + (wm + i * 16 + lr) * 128 +
                                ((kk * 64 + lg * 16) ^ sx));
#pragma unroll
      for (int j = 0; j < 2; ++j)
        b[j] = *(const bf16x8*)((const char*)Bs + (wn + j * 16 + lr) * 128 +
                                ((kk * 64 + lg * 16) ^ sx));
#pragma unroll
      for (int i = 0; i < 4; ++i)
#pragma unroll
        for (int j = 0; j < 2; ++j)
          acc[i][j] = __builtin_amdgcn_mfma_f32_16x16x32_bf16(a[i], b[j], acc[i][j], 0, 0, 0);
    }
    __syncthreads();
  }

#pragma unroll
  for (int i = 0; i < 4; ++i) {
#pragma unroll
    for (int j = 0; j < 2; ++j) {
      int col = n0 + wn + j * 16 + lr;
      float bb = bias[col];
#pragma unroll
      for (int ii = 0; ii < 4; ++ii) {
        int row = m0 + wm + i * 16 + lg * 4 + ii;
        out[(size_t)row * D_MODEL + col] = acc[i][j][ii] + bb;
      }
    }
  }
}

// ------------------------------------------------------------------
// Flash attention, transposed-score form, LDS-staged K/V, NO-MAX softmax
// in the exp2 domain (log2e folded into Q scale and bias table).
// 512 threads = 8 waves, 128 q/block, K-tiles of 64, dbuf global_load_lds.
// ------------------------------------------------------------------
#define QBLK 128
#define KVBLK 64
#define NT (SEQ / KVBLK)
#define TBL_N 2175
#define LDP 72

__global__ __launch_bounds__(512, 4) void attn_kernel(const bf16_t* __restrict__ Qa,
                                                      const bf16_t* __restrict__ Ka,
                                                      const bf16_t* __restrict__ Vt,
                                                      const float* __restrict__ rel,
                                                      bf16_t* __restrict__ ctx) {
  __shared__ float rbl[TBL_N + 1];                     // reversed, pre-scaled bias
  __shared__ __align__(16) bf16_t ks[2][KVBLK * 64];   // [k][d], chunk-swizzled
  __shared__ __align__(16) bf16_t vs[2][KVBLK * 64];   // [d][k], chunk-swizzled
  __shared__ __align__(16) bf16_t p_lds[8][16 * LDP];  // per-wave P [q16][k64]

  // bijective XCD swizzle: 512 blocks -> 64 consecutive per XCD (bh-major)
  const int f = blockIdx.x;
  const int nf = (f & 7) * 64 + (f >> 3);
  const int qb = nf & 15, bh = nf >> 4;
  const int h = bh & (HEADS - 1), b2 = bh >> 4;
  const int qbase = qb * QBLK;
  const int t = threadIdx.x, w = t >> 6, l = t & 63, lr = l & 15, lg = l >> 4;

  const bf16_t* Qbh = Qa + (size_t)bh * SEQ * D_K;
  const bf16_t* Kbh = Ka + (size_t)bh * SEQ * D_K;
  const bf16_t* Vbh = Vt + (size_t)bh * D_K * SEQ;

  // reversed bias table: rbl[j] = log2e * rel_head[qbase + 2174 - j]
  for (int j = t; j < TBL_N; j += 512)
    rbl[j] = LOG2E * rel[(size_t)(qbase + (TBL_N - 1) - j) * HEADS + h];

  // staging: thread t -> 16B chunk (row=t>>3, physchunk=t&7);
  // phys chunk holds source col16 = (t&7) ^ (row&7)  (read-side XOR matches)
  const int srow = t >> 3;
  const int scol = (((t & 7) ^ (srow & 7)) << 3);
  const int sldsoff = w * 512;

  const int qloc = w * 16 + lr;  // this lane's q (block-local)
  bf16x8 qf[2];
#pragma unroll
  for (int kk = 0; kk < 2; ++kk)
    qf[kk] = *(const bf16x8*)(&Qbh[(size_t)(qbase + qloc) * D_K + kk * 32 + lg * 8]);

  bf16x8 ones;
#pragma unroll
  for (int e = 0; e < 8; ++e) ones[e] = (bf16_t)1.0f;

  GLDS16(Kbh + (size_t)srow * D_K + scol, ks[0] + sldsoff);
  GLDS16(Vbh + (size_t)srow * SEQ + scol, vs[0] + sldsoff);
  __syncthreads();  // drains staging vmcnt + covers rbl

  f32x4 acc_o[4] = {};  // acc_o[c][ii] = O[d = c*16 + lg*4 + ii][q = qloc]
  f32x4 l_acc = {};     // all entries = running denominator for q = qloc
  bf16_t* pw = p_lds[w];
  const int sw = (lr & 7) << 4;          // read-side chunk XOR
  const int roff = 127 - qloc + lg * 4;  // reversed-table base offset

  for (int it = 0; it < NT; ++it) {
    const int cur = it & 1;
    const int kt = it * KVBLK;
    if (it + 1 < NT) {
      const int ktn = kt + KVBLK;
      GLDS16(Kbh + (size_t)(ktn + srow) * D_K + scol, ks[cur ^ 1] + sldsoff);
      GLDS16(Vbh + (size_t)srow * SEQ + ktn + scol, vs[cur ^ 1] + sldsoff);
    }
    const char* Kc = (const char*)ks[cur];
    const char* Vc = (const char*)vs[cur];

    // ---- S^T tile in exp2 domain, bias as C-init; P = exp2(z) ----
#pragma unroll
    for (int c = 0; c < 4; ++c) {
      const int r0 = roff + kt + c * 16;
      f32x4 z;
      z[0] = rbl[r0]; z[1] = rbl[r0 + 1]; z[2] = rbl[r0 + 2]; z[3] = rbl[r0 + 3];
#pragma unroll
      for (int kk = 0; kk < 2; ++kk) {
        bf16x8 kf = *(const bf16x8*)(Kc + (c * 16 + lr) * 128 + ((kk * 64 + lg * 16) ^ sw));
        z = __builtin_amdgcn_mfma_f32_16x16x32_bf16(kf, qf[kk], z, 0, 0, 0);
      }
      bf16x4 pv;
#pragma unroll
      for (int i = 0; i < 4; ++i) pv[i] = (bf16_t)__builtin_amdgcn_exp2f(z[i]);
      *(bf16x4*)(&pw[lr * LDP + c * 16 + lg * 4]) = pv;
    }

    // ---- PV: O^T += V^T_frag x P_frag ; l += ones x P_frag ----
    __builtin_amdgcn_s_setprio(1);
#pragma unroll
    for (int kk = 0; kk < 2; ++kk) {
      bf16x8 pa = *(const bf16x8*)(&pw[lr * LDP + kk * 32 + lg * 8]);
      l_acc = __builtin_amdgcn_mfma_f32_16x16x32_bf16(ones, pa, l_acc, 0, 0, 0);
#pragma unroll
      for (int c = 0; c < 4; ++c) {
        bf16x8 vf = *(const bf16x8*)(Vc + (c * 16 + lr) * 128 + ((kk * 64 + lg * 16) ^ sw));
        acc_o[c] = __builtin_amdgcn_mfma_f32_16x16x32_bf16(vf, pa, acc_o[c], 0, 0, 0);
      }
    }
    __builtin_amdgcn_s_setprio(0);
    __syncthreads();  // stage(it+1) landed; all waves done reading cur
  }

  const float inv = 1.0f / l_acc[0];

  int qg = qbase + qloc;
  size_t base = ((size_t)qg * BATCH + b2) * D_MODEL + h * D_K;
#pragma unroll
  for (int c = 0; c < 4; ++c) {
    bf16x4 ov;
#pragma unroll
    for (int ii = 0; ii < 4; ++ii) ov[ii] = (bf16_t)(acc_o[c][ii] * inv);
    *(bf16x4*)(&ctx[base + c * 16 + lg * 4]) = ov;
  }
}

// ------------------------------------------------------------------
extern "C" void kernel_launch(void* const* d_in, const int* in_sizes, int n_in,
                              void* d_out, int out_size, void* d_ws, size_t ws_size,
                              hipStream_t stream) {
  const float* query = (const float*)d_in[0];
  const float* key_i = (const float*)d_in[1];
  const float* value = (const float*)d_in[2];
  const float* Wq = (const float*)d_in[3];
  const float* bq = (const float*)d_in[4];
  const float* Wk = (const float*)d_in[5];
  const float* bk = (const float*)d_in[6];
  const float* Wv = (const float*)d_in[7];
  const float* bv = (const float*)d_in[8];
  const float* Wo = (const float*)d_in[9];
  const float* bo = (const float*)d_in[10];
  const float* rel = (const float*)d_in[11];
  float* out = (float*)d_out;

  char* ws = (char*)d_ws;
  size_t off = 0;
  auto alloc = [&](size_t bytes) {
    char* p = ws + off;
    off = (off + bytes + 255) & ~(size_t)255;
    return p;
  };
  const size_t nIn = (size_t)MTOT * D_MODEL;
  const size_t nW = (size_t)D_MODEL * D_MODEL;

  bf16_t* Xq = (bf16_t*)alloc(nIn * 2);
  bf16_t* Xk = (bf16_t*)alloc(nIn * 2);
  bf16_t* Xv = (bf16_t*)alloc(nIn * 2);
  bf16_t* Wqkv = (bf16_t*)alloc(3 * nW * 2);  // Wq | Wk | Wv rows, contiguous
  bf16_t* Wob = (bf16_t*)alloc(nW * 2);
  bf16_t* qa = (bf16_t*)alloc(nIn * 2);   // [B,H,S,64]
  bf16_t* ka = (bf16_t*)alloc(nIn * 2);   // [B,H,S,64]
  bf16_t* vt = (bf16_t*)alloc(nIn * 2);   // [B,H,64,S]
  bf16_t* ctx = (bf16_t*)alloc(nIn * 2);  // [M,1024]

  cvt4_kernel<<<dim3(nIn / 2048, 3), 256, 0, stream>>>(query, key_i, value, value, Xq, Xk,
                                                       Xv, Xv, (int)nIn);
  cvt4_kernel<<<dim3(nW / 2048, 4), 256, 0, stream>>>(Wq, Wk, Wv, Wo, Wqkv, Wqkv + nW,
                                                      Wqkv + 2 * nW, Wob, (int)nW);

  gemm_qkv<<<dim3(768), 256, 0, stream>>>(Xq, Xk, Xv, Wqkv, bq, bk, bv, qa, ka, vt);

  attn_kernel<<<dim3(512), 512, 0, stream>>>(qa, ka, vt, rel, ctx);

  gemm_out<<<dim3(256), 512, 0, stream>>>(ctx, Wob, bo, out);
}

// Round 7
// 138.163 us; speedup vs baseline: 2.5678x; 1.0265x over previous
//
#include <hip/hip_runtime.h>
#include <hip/hip_bf16.h>

typedef __bf16 bf16_t;
typedef __bf16 bf16x8 __attribute__((ext_vector_type(8)));
typedef __bf16 bf16x4 __attribute__((ext_vector_type(4)));
typedef float f32x4 __attribute__((ext_vector_type(4)));

#define D_MODEL 1024
#define HEADS 16
#define D_K 64
#define SEQ 2048
#define BATCH 2
#define MTOT (SEQ * BATCH) /* 4096 */
#define LOG2E 1.4426950408889634f
#define QSCALE (0.125f * LOG2E) /* fold softmax scale AND log2e into Q */

// async global->LDS, 16B per lane; LDS dest = wave-uniform base + lane*16
#define GLDS16(g, l)                                                        \
  __builtin_amdgcn_global_load_lds(                                        \
      (const __attribute__((address_space(1))) unsigned int*)(g),          \
      (__attribute__((address_space(3))) unsigned int*)(l), 16, 0, 0)

// ------------------------------------------------------------------
// fp32 -> bf16 converts, batched (up to 4 arrays per launch)
// ------------------------------------------------------------------
__global__ __launch_bounds__(256) void cvt4_kernel(const float* s0, const float* s1,
                                                   const float* s2, const float* s3,
                                                   bf16_t* d0, bf16_t* d1, bf16_t* d2,
                                                   bf16_t* d3, int n) {
  const float* s; bf16_t* d;
  switch (blockIdx.y) {
    case 0: s = s0; d = d0; break;
    case 1: s = s1; d = d1; break;
    case 2: s = s2; d = d2; break;
    default: s = s3; d = d3; break;
  }
  int i = (blockIdx.x * 256 + threadIdx.x) * 8;
  if (i >= n) return;
  float4 a = *(const float4*)(s + i);
  float4 b = *(const float4*)(s + i + 4);
  bf16x8 v;
  v[0] = (bf16_t)a.x; v[1] = (bf16_t)a.y; v[2] = (bf16_t)a.z; v[3] = (bf16_t)a.w;
  v[4] = (bf16_t)b.x; v[5] = (bf16_t)b.y; v[6] = (bf16_t)b.z; v[7] = (bf16_t)b.w;
  *(bf16x8*)(d + i) = v;
}

// ------------------------------------------------------------------
// Fused QKV projection GEMM, 2-phase double-buffered (T3 minimum form):
// stage(t+1) issued BEFORE compute(t); single vmcnt-draining barrier per
// K-step hides staging latency under MFMA. XCD row-panel clustering +
// T2 LDS XOR swizzle (pre-swizzled global source, rule 21).
// Q out: [B,H,S,64] * QSCALE; K out: [B,H,S,64]; V out: [B,H,64,S].
// ------------------------------------------------------------------
__global__ __launch_bounds__(256) void gemm_qkv(const bf16_t* __restrict__ Xq,
                                                const bf16_t* __restrict__ Xk,
                                                const bf16_t* __restrict__ Xv,
                                                const bf16_t* __restrict__ Wqkv,
                                                const float* __restrict__ bq,
                                                const float* __restrict__ bk,
                                                const float* __restrict__ bv,
                                                bf16_t* __restrict__ qa,
                                                bf16_t* __restrict__ ka,
                                                bf16_t* __restrict__ vt) {
  __shared__ __align__(16) bf16_t As[2][128 * 64];
  __shared__ __align__(16) bf16_t Bs[2][128 * 64];
  const int t = threadIdx.x;
  const int f = blockIdx.x;
  const int xcd = f & 7, fi = f >> 3;
  const int by = xcd * 4 + (fi & 3);  // row-panel, clustered per XCD
  const int bxi = fi >> 2;            // 0..23 col-block (seg-major)
  const int seg = bxi >> 3;           // 0=Q 1=K 2=V
  const bf16_t* X = seg == 0 ? Xq : (seg == 1 ? Xk : Xv);
  const float* bias = seg == 0 ? bq : (seg == 1 ? bk : bv);
  const float scale = seg == 0 ? QSCALE : 1.0f;
  const int m0 = by * 128;
  const int n0g = bxi * 128;  // global col in [0,3072)
  const int w = t >> 6, l = t & 63, lr = l & 15, lg = l >> 4;
  const int wm = (w >> 1) * 64, wn = (w & 1) * 64;

  f32x4 acc[4][4] = {};

  // staging geometry: chunk idx = p*256+t -> phys (row=idx>>3, c=idx&7);
  // source col chunk = c ^ (row&7)  (T2 pre-swizzled source)
  const int srow0 = t >> 3;
  const int sck = (((t & 7) ^ (srow0 & 7)) << 3);
  const int sx = (lr & 7) << 4;  // read-side XOR (row&7 == lr&7)

#define QKV_STAGE(buf, kt)                                                        \
  {                                                                               \
    _Pragma("unroll") for (int p = 0; p < 4; ++p) {                               \
      int row = (p * 256 + t) >> 3;                                               \
      int wb = (p * 256 + w * 64) * 8;                                            \
      GLDS16(&X[(size_t)(m0 + row) * D_MODEL + (kt) + sck], As[buf] + wb);        \
      GLDS16(&Wqkv[(size_t)(n0g + row) * D_MODEL + (kt) + sck], Bs[buf] + wb);    \
    }                                                                             \
  }

  QKV_STAGE(0, 0);
  __syncthreads();

  for (int step = 0; step < 16; ++step) {
    const int cur = step & 1;
    if (step + 1 < 16) QKV_STAGE(cur ^ 1, (step + 1) * 64);
#pragma unroll
    for (int kk = 0; kk < 2; ++kk) {
      bf16x8 a[4], b[4];
#pragma unroll
      for (int i = 0; i < 4; ++i)
        a[i] = *(const bf16x8*)((const char*)As[cur] + (wm + i * 16 + lr) * 128 +
                                ((kk * 64 + lg * 16) ^ sx));
#pragma unroll
      for (int j = 0; j < 4; ++j)
        b[j] = *(const bf16x8*)((const char*)Bs[cur] + (wn + j * 16 + lr) * 128 +
                                ((kk * 64 + lg * 16) ^ sx));
#pragma unroll
      for (int i = 0; i < 4; ++i)
#pragma unroll
        for (int j = 0; j < 4; ++j)
          acc[i][j] = __builtin_amdgcn_mfma_f32_16x16x32_bf16(a[i], b[j], acc[i][j], 0, 0, 0);
    }
    __syncthreads();  // waves done reading cur; stage(cur^1) drained
  }
#undef QKV_STAGE

  // epilogue: D layout col = lane&15, row = (lane>>4)*4 + reg  [m89-verified]
#pragma unroll
  for (int i = 0; i < 4; ++i) {
#pragma unroll
    for (int j = 0; j < 4; ++j) {
      int lc = ((n0g + wn) & 1023) + j * 16 + lr;  // segment-local col
      float bb = bias[lc];
      int h = lc >> 6, d = lc & 63;
#pragma unroll
      for (int ii = 0; ii < 4; ++ii) {
        int row = m0 + wm + i * 16 + lg * 4 + ii;
        float v = (acc[i][j][ii] + bb) * scale;
        int s = row >> 1, b2 = row & 1;
        if (seg == 2)
          vt[(((size_t)(b2 * HEADS + h) * D_K) + d) * SEQ + s] = (bf16_t)v;
        else if (seg == 1)
          ka[(((size_t)(b2 * HEADS + h) * SEQ) + s) * D_K + d] = (bf16_t)v;
        else
          qa[(((size_t)(b2 * HEADS + h) * SEQ) + s) * D_K + d] = (bf16_t)v;
      }
    }
  }
}

// ------------------------------------------------------------------
// Output GEMM: out[m][n] = ctx[m,:].Wo[n,:] + bo[n], fp32 out.
// 128x128 tile, 512 threads / 8 waves (2x4), 2-phase double-buffered,
// XCD row-panel clustering + T2 LDS swizzle.
// ------------------------------------------------------------------
__global__ __launch_bounds__(512) void gemm_out(const bf16_t* __restrict__ X,
                                                const bf16_t* __restrict__ W,
                                                const float* __restrict__ bias,
                                                float* __restrict__ out) {
  __shared__ __align__(16) bf16_t As[2][128 * 64];
  __shared__ __align__(16) bf16_t Bs[2][128 * 64];
  const int t = threadIdx.x;
  const int f = blockIdx.x;
  const int xcd = f & 7, fi = f >> 3;
  const int by = xcd * 4 + (fi & 3);
  const int bx = fi >> 2;  // 0..7
  const int m0 = by * 128, n0 = bx * 128;
  const int w = t >> 6, l = t & 63, lr = l & 15, lg = l >> 4;
  const int wm = (w >> 2) * 64, wn = (w & 3) * 32;
  const int srow0 = t >> 3;
  const int sck = (((t & 7) ^ (srow0 & 7)) << 3);
  const int sx = (lr & 7) << 4;

  f32x4 acc[4][2] = {};

#define OUT_STAGE(buf, kt)                                                      \
  {                                                                             \
    _Pragma("unroll") for (int p = 0; p < 2; ++p) {                             \
      int row = (p * 512 + t) >> 3;                                             \
      int wb = (p * 512 + w * 64) * 8;                                          \
      GLDS16(&X[(size_t)(m0 + row) * D_MODEL + (kt) + sck], As[buf] + wb);      \
      GLDS16(&W[(size_t)(n0 + row) * D_MODEL + (kt) + sck], Bs[buf] + wb);      \
    }                                                                           \
  }

  OUT_STAGE(0, 0);
  __syncthreads();

  for (int step = 0; step < 16; ++step) {
    const int cur = step & 1;
    if (step + 1 < 16) OUT_STAGE(cur ^ 1, (step + 1) * 64);
#pragma unroll
    for (int kk = 0; kk < 2; ++kk) {
      bf16x8 a[4], b[2];
#pragma unroll
      for (int i = 0; i < 4; ++i)
        a[i] = *(const bf16x8*)((const char*)As[cur] + (wm + i * 16 + lr) * 128 +
                                ((kk * 64 + lg * 16) ^ sx));
#pragma unroll
      for (int j = 0; j < 2; ++j)
        b[j] = *(const bf16x8*)((const char*)Bs[cur] + (wn + j * 16 + lr) * 128 +
                                ((kk * 64 + lg * 16) ^ sx));
#pragma unroll
      for (int i = 0; i < 4; ++i)
#pragma unroll
        for (int j = 0; j < 2; ++j)
          acc[i][j] = __builtin_amdgcn_mfma_f32_16x16x32_bf16(a[i], b[j], acc[i][j], 0, 0, 0);
    }
    __syncthreads();
  }
#undef OUT_STAGE

#pragma unroll
  for (int i = 0; i < 4; ++i) {
#pragma unroll
    for (int j = 0; j < 2; ++j) {
      int col = n0 + wn + j * 16 + lr;
      float bb = bias[col];
#pragma unroll
      for (int ii = 0; ii < 4; ++ii) {
        int row = m0 + wm + i * 16 + lg * 4 + ii;
        out[(size_t)row * D_MODEL + col] = acc[i][j][ii] + bb;
      }
    }
  }
}

// ------------------------------------------------------------------
// Flash attention, transposed-score form, LDS-staged K/V, NO-MAX softmax
// in the exp2 domain (log2e folded into Q scale and bias table).
// 512 threads = 8 waves, 128 q/block, K-tiles of 64, dbuf global_load_lds.
// ------------------------------------------------------------------
#define QBLK 128
#define KVBLK 64
#define NT (SEQ / KVBLK)
#define TBL_N 2175
#define LDP 72

__global__ __launch_bounds__(512, 4) void attn_kernel(const bf16_t* __restrict__ Qa,
                                                      const bf16_t* __restrict__ Ka,
                                                      const bf16_t* __restrict__ Vt,
                                                      const float* __restrict__ rel,
                                                      bf16_t* __restrict__ ctx) {
  __shared__ float rbl[TBL_N + 1];                     // reversed, pre-scaled bias
  __shared__ __align__(16) bf16_t ks[2][KVBLK * 64];   // [k][d], chunk-swizzled
  __shared__ __align__(16) bf16_t vs[2][KVBLK * 64];   // [d][k], chunk-swizzled
  __shared__ __align__(16) bf16_t p_lds[8][16 * LDP];  // per-wave P [q16][k64]

  // bijective XCD swizzle: 512 blocks -> 64 consecutive per XCD (bh-major)
  const int f = blockIdx.x;
  const int nf = (f & 7) * 64 + (f >> 3);
  const int qb = nf & 15, bh = nf >> 4;
  const int h = bh & (HEADS - 1), b2 = bh >> 4;
  const int qbase = qb * QBLK;
  const int t = threadIdx.x, w = t >> 6, l = t & 63, lr = l & 15, lg = l >> 4;

  const bf16_t* Qbh = Qa + (size_t)bh * SEQ * D_K;
  const bf16_t* Kbh = Ka + (size_t)bh * SEQ * D_K;
  const bf16_t* Vbh = Vt + (size_t)bh * D_K * SEQ;

  // reversed bias table: rbl[j] = log2e * rel_head[qbase + 2174 - j]
  for (int j = t; j < TBL_N; j += 512)
    rbl[j] = LOG2E * rel[(size_t)(qbase + (TBL_N - 1) - j) * HEADS + h];

  // staging: thread t -> 16B chunk (row=t>>3, physchunk=t&7);
  // phys chunk holds source col16 = (t&7) ^ (row&7)  (read-side XOR matches)
  const int srow = t >> 3;
  const int scol = (((t & 7) ^ (srow & 7)) << 3);
  const int sldsoff = w * 512;

  const int qloc = w * 16 + lr;  // this lane's q (block-local)
  bf16x8 qf[2];
#pragma unroll
  for (int kk = 0; kk < 2; ++kk)
    qf[kk] = *(const bf16x8*)(&Qbh[(size_t)(qbase + qloc) * D_K + kk * 32 + lg * 8]);

  bf16x8 ones;
#pragma unroll
  for (int e = 0; e < 8; ++e) ones[e] = (bf16_t)1.0f;

  GLDS16(Kbh + (size_t)srow * D_K + scol, ks[0] + sldsoff);
  GLDS16(Vbh + (size_t)srow * SEQ + scol, vs[0] + sldsoff);
  __syncthreads();  // drains staging vmcnt + covers rbl

  f32x4 acc_o[4] = {};  // acc_o[c][ii] = O[d = c*16 + lg*4 + ii][q = qloc]
  f32x4 l_acc = {};     // all entries = running denominator for q = qloc
  bf16_t* pw = p_lds[w];
  const int sw = (lr & 7) << 4;          // read-side chunk XOR
  const int roff = 127 - qloc + lg * 4;  // reversed-table base offset

  for (int it = 0; it < NT; ++it) {
    const int cur = it & 1;
    const int kt = it * KVBLK;
    if (it + 1 < NT) {
      const int ktn = kt + KVBLK;
      GLDS16(Kbh + (size_t)(ktn + srow) * D_K + scol, ks[cur ^ 1] + sldsoff);
      GLDS16(Vbh + (size_t)srow * SEQ + ktn + scol, vs[cur ^ 1] + sldsoff);
    }
    const char* Kc = (const char*)ks[cur];
    const char* Vc = (const char*)vs[cur];

    // ---- S^T tile in exp2 domain, bias as C-init; P = exp2(z) ----
#pragma unroll
    for (int c = 0; c < 4; ++c) {
      const int r0 = roff + kt + c * 16;
      f32x4 z;
      z[0] = rbl[r0]; z[1] = rbl[r0 + 1]; z[2] = rbl[r0 + 2]; z[3] = rbl[r0 + 3];
#pragma unroll
      for (int kk = 0; kk < 2; ++kk) {
        bf16x8 kf = *(const bf16x8*)(Kc + (c * 16 + lr) * 128 + ((kk * 64 + lg * 16) ^ sw));
        z = __builtin_amdgcn_mfma_f32_16x16x32_bf16(kf, qf[kk], z, 0, 0, 0);
      }
      bf16x4 pv;
#pragma unroll
      for (int i = 0; i < 4; ++i) pv[i] = (bf16_t)__builtin_amdgcn_exp2f(z[i]);
      *(bf16x4*)(&pw[lr * LDP + c * 16 + lg * 4]) = pv;
    }

    // ---- PV: O^T += V^T_frag x P_frag ; l += ones x P_frag ----
    __builtin_amdgcn_s_setprio(1);
#pragma unroll
    for (int kk = 0; kk < 2; ++kk) {
      bf16x8 pa = *(const bf16x8*)(&pw[lr * LDP + kk * 32 + lg * 8]);
      l_acc = __builtin_amdgcn_mfma_f32_16x16x32_bf16(ones, pa, l_acc, 0, 0, 0);
#pragma unroll
      for (int c = 0; c < 4; ++c) {
        bf16x8 vf = *(const bf16x8*)(Vc + (c * 16 + lr) * 128 + ((kk * 64 + lg * 16) ^ sw));
        acc_o[c] = __builtin_amdgcn_mfma_f32_16x16x32_bf16(vf, pa, acc_o[c], 0, 0, 0);
      }
    }
    __builtin_amdgcn_s_setprio(0);
    __syncthreads();  // stage(it+1) landed; all waves done reading cur
  }

  const float inv = 1.0f / l_acc[0];

  int qg = qbase + qloc;
  size_t base = ((size_t)qg * BATCH + b2) * D_MODEL + h * D_K;
#pragma unroll
  for (int c = 0; c < 4; ++c) {
    bf16x4 ov;
#pragma unroll
    for (int ii = 0; ii < 4; ++ii) ov[ii] = (bf16_t)(acc_o[c][ii] * inv);
    *(bf16x4*)(&ctx[base + c * 16 + lg * 4]) = ov;
  }
}

// ------------------------------------------------------------------
extern "C" void kernel_launch(void* const* d_in, const int* in_sizes, int n_in,
                              void* d_out, int out_size, void* d_ws, size_t ws_size,
                              hipStream_t stream) {
  const float* query = (const float*)d_in[0];
  const float* key_i = (const float*)d_in[1];
  const float* value = (const float*)d_in[2];
  const float* Wq = (const float*)d_in[3];
  const float* bq = (const float*)d_in[4];
  const float* Wk = (const float*)d_in[5];
  const float* bk = (const float*)d_in[6];
  const float* Wv = (const float*)d_in[7];
  const float* bv = (const float*)d_in[8];
  const float* Wo = (const float*)d_in[9];
  const float* bo = (const float*)d_in[10];
  const float* rel = (const float*)d_in[11];
  float* out = (float*)d_out;

  char* ws = (char*)d_ws;
  size_t off = 0;
  auto alloc = [&](size_t bytes) {
    char* p = ws + off;
    off = (off + bytes + 255) & ~(size_t)255;
    return p;
  };
  const size_t nIn = (size_t)MTOT * D_MODEL;
  const size_t nW = (size_t)D_MODEL * D_MODEL;

  bf16_t* Xq = (bf16_t*)alloc(nIn * 2);
  bf16_t* Xk = (bf16_t*)alloc(nIn * 2);
  bf16_t* Xv = (bf16_t*)alloc(nIn * 2);
  bf16_t* Wqkv = (bf16_t*)alloc(3 * nW * 2);  // Wq | Wk | Wv rows, contiguous
  bf16_t* Wob = (bf16_t*)alloc(nW * 2);
  bf16_t* qa = (bf16_t*)alloc(nIn * 2);   // [B,H,S,64]
  bf16_t* ka = (bf16_t*)alloc(nIn * 2);   // [B,H,S,64]
  bf16_t* vt = (bf16_t*)alloc(nIn * 2);   // [B,H,64,S]
  bf16_t* ctx = (bf16_t*)alloc(nIn * 2);  // [M,1024]

  cvt4_kernel<<<dim3(nIn / 2048, 3), 256, 0, stream>>>(query, key_i, value, value, Xq, Xk,
                                                       Xv, Xv, (int)nIn);
  cvt4_kernel<<<dim3(nW / 2048, 4), 256, 0, stream>>>(Wq, Wk, Wv, Wo, Wqkv, Wqkv + nW,
                                                      Wqkv + 2 * nW, Wob, (int)nW);

  gemm_qkv<<<dim3(768), 256, 0, stream>>>(Xq, Xk, Xv, Wqkv, bq, bk, bv, qa, ka, vt);

  attn_kernel<<<dim3(512), 512, 0, stream>>>(qa, ka, vt, rel, ctx);

  gemm_out<<<dim3(256), 512, 0, stream>>>(ctx, Wob, bo, out);
}